// Round 7
// baseline (3019.977 us; speedup 1.0000x reference)
//
#include <hip/hip_runtime.h>
#include <stdint.h>
#include <math.h>

// Problem constants
#define NN    50000       // N_NODES
#define NE    400000      // N_EDGES
#define NL    50000       // N_LINKS
#define TOT   12800000    // NN*256

#define JAX_PARTITIONABLE 1

struct K8 { uint32_t a[4]; uint32_t b[4]; };

// ---------------- Threefry-2x32 (20 rounds) ----------------
__host__ __device__ inline uint32_t rotl32(uint32_t x, int r){ return (x<<r)|(x>>(32-r)); }

__host__ __device__ inline void tf2x32(uint32_t k0, uint32_t k1, uint32_t x0, uint32_t x1,
                                       uint32_t &o0, uint32_t &o1) {
  uint32_t k2 = k0 ^ k1 ^ 0x1BD11BDAu;
  x0 += k0; x1 += k1;
#define TFR(r) { x0 += x1; x1 = rotl32(x1,(r)); x1 ^= x0; }
  TFR(13) TFR(15) TFR(26) TFR(6)
  x0 += k1; x1 += k2 + 1u;
  TFR(17) TFR(29) TFR(16) TFR(24)
  x0 += k2; x1 += k0 + 2u;
  TFR(13) TFR(15) TFR(26) TFR(6)
  x0 += k0; x1 += k1 + 3u;
  TFR(17) TFR(29) TFR(16) TFR(24)
  x0 += k1; x1 += k2 + 4u;
  TFR(13) TFR(15) TFR(26) TFR(6)
  x0 += k2; x1 += k0 + 5u;
#undef TFR
  o0 = x0; o1 = x1;
}

__device__ inline float u01(uint32_t b){
  return __uint_as_float((b>>9) | 0x3f800000u) - 1.0f;   // [1,2) - 1, exact
}

__device__ inline uint32_t jax_bits32(uint32_t ka, uint32_t kb, uint32_t i, uint32_t total){
#if JAX_PARTITIONABLE
  uint32_t o0,o1; tf2x32(ka,kb, 0u, i, o0,o1); return o0^o1;
#else
  uint32_t h = total>>1; uint32_t o0,o1;
  if (i < h){ tf2x32(ka,kb, i, i+h, o0,o1); return o0; }
  else      { tf2x32(ka,kb, i-h, i, o0,o1); return o1; }
#endif
}

__device__ inline double shflxor_d(double x, int m){
  union { double d; int i[2]; } u; u.d = x;
  u.i[0] = __shfl_xor(u.i[0], m, 64);
  u.i[1] = __shfl_xor(u.i[1], m, 64);
  return u.d;
}

// exact fp32 LIF step: v = fl(fl(v*0.5)+a); d = fl(v-0.2); s=(d>=0); v = s?d:v
__device__ inline bool lif32(float &v, float a){
  v = __fadd_rn(__fmul_rn(v, 0.5f), a);
  float d = __fsub_rn(v, 0.2f);
  bool s = (d >= 0.0f);
  v = s ? d : v;
  return s;
}

// force a value to live in a VGPR (defeats scalar-ization of uniform values)
#define FORCE_V(x) asm volatile("" : "+v"(x))

// wr if bit b of w set, else +0.0f — v_bfe_i32 + v_and_b32 (2 full-rate VALU ops)
__device__ inline float bitmaskf(uint32_t w, int b, float wr){
#if __has_builtin(__builtin_amdgcn_sbfe)
  int m = __builtin_amdgcn_sbfe((int)w, b, 1);       // 0x00000000 or 0xFFFFFFFF
#else
  int m = ((int)(w << (31-b))) >> 31;
#endif
  return __int_as_float(__float_as_int(wr) & m);
}

// ---------------- CSR build (by dst), deterministic edge order ----------------
__global__ __launch_bounds__(256) void k_hist(const int* __restrict__ dst, int* __restrict__ cnt){
  int e = blockIdx.x*256 + threadIdx.x;
  if (e < NE) atomicAdd(&cnt[dst[e]], 1);
}

__global__ __launch_bounds__(1024) void k_scan(const int* __restrict__ cnt,
    int* __restrict__ rp, int* __restrict__ cur){
  __shared__ int buf[1024];
  __shared__ int carry;
  int tid = threadIdx.x;
  if (tid==0) carry = 0;
  __syncthreads();
  for (int base=0; base<NN; base+=1024){
    int v = (base+tid < NN) ? cnt[base+tid] : 0;
    buf[tid] = v; __syncthreads();
    for (int off=1; off<1024; off<<=1){
      int t = (tid>=off) ? buf[tid-off] : 0;
      __syncthreads();
      buf[tid] += t;
      __syncthreads();
    }
    int excl = buf[tid] - v + carry;
    if (base+tid < NN){ rp[base+tid] = excl; cur[base+tid] = excl; }
    __syncthreads();
    if (tid==0) carry += buf[1023];
    __syncthreads();
  }
  if (tid==0) rp[NN] = NE;
}

__global__ __launch_bounds__(256) void k_scatter(const int* __restrict__ dst,
    int* __restrict__ cur, int* __restrict__ eidx){
  int e = blockIdx.x*256 + threadIdx.x;
  if (e < NE){ int p = atomicAdd(&cur[dst[e]], 1); eidx[p] = e; }
}

__global__ __launch_bounds__(256) void k_sortrow(const int* __restrict__ rp,
    int* __restrict__ eidx, const int* __restrict__ esrc, const float* __restrict__ ew,
    int* __restrict__ csrc, float* __restrict__ cw){
  int n = blockIdx.x*256 + threadIdx.x;
  if (n >= NN) return;
  int lo = rp[n], hi = rp[n+1];
  for (int a=lo+1; a<hi; a++){
    int k = eidx[a]; int b = a-1;
    while (b>=lo && eidx[b]>k){ eidx[b+1]=eidx[b]; b--; }
    eidx[b+1] = k;
  }
  for (int p=lo; p<hi; p++){ int e = eidx[p]; csrc[p] = esrc[e]; cw[p] = ew[e]; }
}

// Plane layouts (t innermost, 32B per (node,word)):
//   inpb/hs0b/zs0b : [node][w(4)][t(4)]   (NN*16 words)
//   hs1b           : [node][w(8)][t(4)]   (NN*32 words)
//   zs1b           : [node][w(2)][t(4)]   (NN*8  words)

// ---------------- Stage A: inp(t) = poisson(x, k1[t]) ----------------
__global__ __launch_bounds__(256) void k_pois_x(const float* __restrict__ x,
    uint64_t* __restrict__ bits, K8 K){
  int n = blockIdx.x, f = threadIdx.x;
  uint32_t i = (uint32_t)n*256u + (uint32_t)f;
  float xv = x[i];
  uint64_t pack[4];
  #pragma unroll
  for (int t=0;t<4;t++){
    bool b = (u01(jax_bits32(K.a[t],K.b[t], i, TOT)) <= xv);
    pack[t] = __ballot(b);
  }
  if ((f & 63)==0){
    uint64_t* dst = bits + ((size_t)n*4 + (f>>6))*4;
    #pragma unroll
    for (int t=0;t<4;t++) dst[t] = pack[t];
  }
}

// ---------------- Stage B: h0(t) fp32 gather (edge order) + poisson(h0,k2) ----------------
__global__ __launch_bounds__(256) void k_h0(const int* __restrict__ rp,
    const int* __restrict__ csrc, const float* __restrict__ cw,
    const uint64_t* __restrict__ inb, uint64_t* __restrict__ outb, K8 K){
  int n = blockIdx.x, f = threadIdx.x;
  int wi = f>>6, sh = f&63;
  int lo = rp[n], hi = rp[n+1];
  float a[4] = {0.f,0.f,0.f,0.f};
  for (int p=lo;p<hi;p++){
    int s = csrc[p]; float w = cw[p];
    const uint64_t* bp = inb + ((size_t)s*4 + wi)*4;   // 4 t-words, 32B contiguous
    uint64_t w0=bp[0], w1=bp[1], w2=bp[2], w3=bp[3];
    a[0] = __fadd_rn(a[0], ((w0>>sh)&1ull) ? w : 0.0f);
    a[1] = __fadd_rn(a[1], ((w1>>sh)&1ull) ? w : 0.0f);
    a[2] = __fadd_rn(a[2], ((w2>>sh)&1ull) ? w : 0.0f);
    a[3] = __fadd_rn(a[3], ((w3>>sh)&1ull) ? w : 0.0f);
  }
  uint32_t i = (uint32_t)n*256u + (uint32_t)f;
  uint64_t pack[4];
  #pragma unroll
  for (int t=0;t<4;t++){
    bool b = (u01(jax_bits32(K.a[t],K.b[t], i, TOT)) <= a[t]);
    pack[t] = __ballot(b);
  }
  if (sh==0){
    uint64_t* dst = outb + ((size_t)n*4 + wi)*4;
    #pragma unroll
    for (int t=0;t<4;t++) dst[t] = pack[t];
  }
}

// ---------------- Stage C: z0 = LIF_t(hs0 @ W1)  (K=256, M=256) ----------------
// Per kw: batch-issue ALL loads (16 spike words + 64 weight column values),
// then a pure-VALU unrolled masked-add block (sbfe+and+fadd, 3 ops/pair).
// launch_bounds(...,2) lifts the VGPR cap so wr[64] stays in registers.
__global__ __launch_bounds__(256, 2) void k_z0(const uint64_t* __restrict__ inb,
    const float* __restrict__ W, uint64_t* __restrict__ outb){
  int j = threadIdx.x;
  int n0 = blockIdx.x*4;
  float acc[4][4];                                // [t][i]
  #pragma unroll
  for (int t=0;t<4;t++)
    #pragma unroll
    for (int i=0;i<4;i++) acc[t][i] = 0.0f;

  for (int kw=0;kw<4;kw++){
    uint32_t wlo[4][4], whi[4][4];                // [i][t]
    #pragma unroll
    for (int i=0;i<4;i++){
      const uint64_t* bp = inb + (((size_t)(n0+i))*4 + kw)*4;
      #pragma unroll
      for (int t=0;t<4;t++){
        uint64_t w8 = bp[t];
        wlo[i][t] = (uint32_t)w8;
        whi[i][t] = (uint32_t)(w8>>32);
        FORCE_V(wlo[i][t]); FORCE_V(whi[i][t]);
      }
    }
    const float* Wp = W + (size_t)(kw*64)*256 + j;
    float wr[64];
    #pragma unroll
    for (int q=0;q<64;q++) wr[q] = Wp[(size_t)q*256];   // 64 independent loads
    #pragma unroll
    for (int h=0;h<2;h++){
      #pragma unroll
      for (int q=0;q<32;q++){
        #pragma unroll
        for (int i=0;i<4;i++){
          #pragma unroll
          for (int t=0;t<4;t++){
            uint32_t wv = h ? whi[i][t] : wlo[i][t];
            acc[t][i] = __fadd_rn(acc[t][i], bitmaskf(wv, q, wr[h*32+q]));
          }
        }
      }
    }
  }

  int wi = j>>6;
  #pragma unroll
  for (int i=0;i<4;i++){
    float v = 0.0f;
    uint64_t pack[4];
    #pragma unroll
    for (int t=0;t<4;t++){
      bool s = lif32(v, acc[t][i]);
      pack[t] = __ballot(s);
    }
    if ((j&63)==0){
      uint64_t* dst = outb + (((size_t)(n0+i))*4 + wi)*4;
      #pragma unroll
      for (int t=0;t<4;t++) dst[t] = pack[t];
    }
  }
}

// ---------------- Stage D: h1(t) gather over concat(zs0,hs0), LIF -> hs1 ----------------
__global__ __launch_bounds__(512) void k_h1(const int* __restrict__ rp,
    const int* __restrict__ csrc, const float* __restrict__ cw,
    const uint64_t* __restrict__ zs0b, const uint64_t* __restrict__ hs0b,
    uint64_t* __restrict__ hs1b){
  int n = blockIdx.x, f = threadIdx.x;           // f in [0,512)
  int wi = f>>6, sh = f&63;
  const uint64_t* plane = (wi<4) ? zs0b : hs0b;
  int wo = wi & 3;
  int lo = rp[n], hi = rp[n+1];
  float a[4] = {0.f,0.f,0.f,0.f};
  for (int p=lo;p<hi;p++){
    int s = csrc[p]; float w = cw[p];
    const uint64_t* bp = plane + ((size_t)s*4 + wo)*4;  // 32B contiguous
    uint64_t w0=bp[0], w1=bp[1], w2=bp[2], w3=bp[3];
    a[0] = __fadd_rn(a[0], ((w0>>sh)&1ull) ? w : 0.0f);
    a[1] = __fadd_rn(a[1], ((w1>>sh)&1ull) ? w : 0.0f);
    a[2] = __fadd_rn(a[2], ((w2>>sh)&1ull) ? w : 0.0f);
    a[3] = __fadd_rn(a[3], ((w3>>sh)&1ull) ? w : 0.0f);
  }
  float v = 0.0f;
  uint64_t pack[4];
  #pragma unroll
  for (int t=0;t<4;t++){
    bool s = lif32(v, a[t]);
    pack[t] = __ballot(s);
  }
  if (sh==0){
    uint64_t* dst = hs1b + ((size_t)n*8 + wi)*4;
    #pragma unroll
    for (int t=0;t<4;t++) dst[t] = pack[t];
  }
}

// ---------------- Stage E: z1 = LIF_t(hs1 @ W2)  (K=512, M=128) ----------------
__global__ __launch_bounds__(128, 2) void k_z1(const uint64_t* __restrict__ inb,
    const float* __restrict__ W, uint64_t* __restrict__ outb){
  int j = threadIdx.x;
  int n0 = blockIdx.x*4;
  float acc[4][4];
  #pragma unroll
  for (int t=0;t<4;t++)
    #pragma unroll
    for (int i=0;i<4;i++) acc[t][i] = 0.0f;

  for (int kw=0;kw<8;kw++){
    uint32_t wlo[4][4], whi[4][4];
    #pragma unroll
    for (int i=0;i<4;i++){
      const uint64_t* bp = inb + (((size_t)(n0+i))*8 + kw)*4;
      #pragma unroll
      for (int t=0;t<4;t++){
        uint64_t w8 = bp[t];
        wlo[i][t] = (uint32_t)w8;
        whi[i][t] = (uint32_t)(w8>>32);
        FORCE_V(wlo[i][t]); FORCE_V(whi[i][t]);
      }
    }
    const float* Wp = W + (size_t)(kw*64)*128 + j;
    float wr[64];
    #pragma unroll
    for (int q=0;q<64;q++) wr[q] = Wp[(size_t)q*128];   // 64 independent loads
    #pragma unroll
    for (int h=0;h<2;h++){
      #pragma unroll
      for (int q=0;q<32;q++){
        #pragma unroll
        for (int i=0;i<4;i++){
          #pragma unroll
          for (int t=0;t<4;t++){
            uint32_t wv = h ? whi[i][t] : wlo[i][t];
            acc[t][i] = __fadd_rn(acc[t][i], bitmaskf(wv, q, wr[h*32+q]));
          }
        }
      }
    }
  }

  int wi = j>>6;  // 0 or 1
  #pragma unroll
  for (int i=0;i<4;i++){
    float v = 0.0f;
    uint64_t pack[4];
    #pragma unroll
    for (int t=0;t<4;t++){
      bool s = lif32(v, acc[t][i]);
      pack[t] = __ballot(s);
    }
    if ((j&63)==0){
      uint64_t* dst = outb + (((size_t)(n0+i))*2 + wi)*4;
      #pragma unroll
      for (int t=0;t<4;t++) dst[t] = pack[t];
    }
  }
}

// ---------------- Stage F: decoder + y + sigmoid ----------------
// block = 128 threads: wave0 = row i (ns), wave1 = row i+L (nt); j = DEC column
__global__ __launch_bounds__(128) void k_dec_y(const int* __restrict__ ns,
    const int* __restrict__ nt, const uint64_t* __restrict__ zs1b,
    const float* __restrict__ Wd, const float* __restrict__ bd,
    const float* __restrict__ wrec, float* __restrict__ out){
  int i = blockIdx.x;
  int tid = threadIdx.x;
  int row = tid>>6, j = tid&63;
  int node = row ? nt[i] : ns[i];
  float bdj = bd[j];
  double wrecj = (double)wrec[j];
  __shared__ uint64_t sw[2];

  // load this node's zs1 row: 2 k-groups x 4 t  (64B contiguous)
  uint32_t wlo[2][4], whi[2][4];
  const uint64_t* bp = zs1b + (size_t)node*8;
  #pragma unroll
  for (int g=0;g<2;g++)
    #pragma unroll
    for (int t=0;t<4;t++){
      uint64_t w8 = bp[g*4+t];
      wlo[g][t] = (uint32_t)w8;
      whi[g][t] = (uint32_t)(w8>>32);
      FORCE_V(wlo[g][t]); FORCE_V(whi[g][t]);
    }

  float acc[4] = {0.f,0.f,0.f,0.f};
  #pragma unroll
  for (int g=0;g<2;g++){
    #pragma unroll
    for (int h=0;h<2;h++){
      #pragma unroll
      for (int c=0;c<2;c++){
        float wr[16];
        #pragma unroll
        for (int q=0;q<16;q++) wr[q] = Wd[(size_t)(g*64+h*32+c*16+q)*64 + j];
        #pragma unroll
        for (int q=0;q<16;q++){
          int b = c*16+q;
          #pragma unroll
          for (int t=0;t<4;t++){
            uint32_t wv = h ? whi[g][t] : wlo[g][t];
            acc[t] = __fadd_rn(acc[t], bitmaskf(wv, b, wr[q]));
          }
        }
      }
    }
  }

  float v = 0.0f;
  double ysum = 0.0;
  #pragma unroll
  for (int t=0;t<4;t++){
    float a = __fadd_rn(acc[t], bdj);
    bool s = lif32(v, a);
    uint64_t bw = __ballot(s);
    if (j==0) sw[row] = bw;
    __syncthreads();
    uint64_t m = sw[0] & sw[1];
    __syncthreads();
    double term = ((m>>j)&1ull) ? wrecj : 0.0;
    #pragma unroll
    for (int off=1; off<64; off<<=1) term += shflxor_d(term, off);
    ysum += term;
  }
  if (tid==0) out[i] = (float)(1.0/(1.0 + exp(-0.25*ysum)));
}

// ---------------- Launcher ----------------
extern "C" void kernel_launch(void* const* d_in, const int* in_sizes, int n_in,
                              void* d_out, int out_size, void* d_ws, size_t ws_size,
                              hipStream_t stream) {
  const float* x    = (const float*)d_in[0];
  const float* W1   = (const float*)d_in[1];
  const float* W2   = (const float*)d_in[2];
  const float* Wd   = (const float*)d_in[3];
  const float* bd   = (const float*)d_in[4];
  const float* wrec = (const float*)d_in[5];
  const float* ew   = (const float*)d_in[6];
  const int* esrc   = (const int*)d_in[7];
  const int* edst   = (const int*)d_in[8];
  const int* ns     = (const int*)d_in[9];
  const int* nt     = (const int*)d_in[10];
  float* out = (float*)d_out;
  (void)in_sizes; (void)n_in; (void)out_size; (void)ws_size;

  // workspace layout (~41 MB)
  char* p = (char*)d_ws;
  uint64_t* inpb = (uint64_t*)p; p += (size_t)NN*16*8;
  uint64_t* hs0b = (uint64_t*)p; p += (size_t)NN*16*8;
  uint64_t* zs0b = (uint64_t*)p; p += (size_t)NN*16*8;
  uint64_t* hs1b = (uint64_t*)p; p += (size_t)NN*32*8;
  uint64_t* zs1b = (uint64_t*)p; p += (size_t)NN*8*8;
  int*   eidx = (int*)p;   p += (size_t)NE*4;
  int*   csrc = (int*)p;   p += (size_t)NE*4;
  float* cw   = (float*)p; p += (size_t)NE*4;
  int*   cnt  = (int*)p;   p += (size_t)(NN+2)*4;
  int*   rp   = (int*)p;   p += (size_t)(NN+2)*4;
  int*   cur  = (int*)p;   p += (size_t)(NN+2)*4;

  // host-side key chain: key=(0,42); kt=fold_in(key,t); k1,k2=split(kt)
  K8 K1, K2;
  for (int t=0;t<4;t++){
    uint32_t kt0,kt1;
    tf2x32(0u, 42u, 0u, (uint32_t)t, kt0, kt1);
#if JAX_PARTITIONABLE
    tf2x32(kt0, kt1, 0u, 0u, K1.a[t], K1.b[t]);
    tf2x32(kt0, kt1, 0u, 1u, K2.a[t], K2.b[t]);
#else
    uint32_t A0,B0,A1,B1;
    tf2x32(kt0, kt1, 0u, 2u, A0, B0);
    tf2x32(kt0, kt1, 1u, 3u, A1, B1);
    K1.a[t]=A0; K1.b[t]=A1; K2.a[t]=B0; K2.b[t]=B1;
#endif
  }

  // CSR build (deterministic via per-row sort by edge id)
  hipMemsetAsync(cnt, 0, (size_t)NN*4, stream);
  k_hist   <<<(NE+255)/256, 256, 0, stream>>>(edst, cnt);
  k_scan   <<<1, 1024, 0, stream>>>(cnt, rp, cur);
  k_scatter<<<(NE+255)/256, 256, 0, stream>>>(edst, cur, eidx);
  k_sortrow<<<(NN+255)/256, 256, 0, stream>>>(rp, eidx, esrc, ew, csrc, cw);

  // stage-major pipeline, all T=4 per kernel, LIF state in registers (fp32)
  k_pois_x<<<NN, 256, 0, stream>>>(x, inpb, K1);
  k_h0    <<<NN, 256, 0, stream>>>(rp, csrc, cw, inpb, hs0b, K2);
  k_z0    <<<NN/4, 256, 0, stream>>>(hs0b, W1, zs0b);
  k_h1    <<<NN, 512, 0, stream>>>(rp, csrc, cw, zs0b, hs0b, hs1b);
  k_z1    <<<NN/4, 128, 0, stream>>>(hs1b, W2, zs1b);
  k_dec_y <<<NL, 128, 0, stream>>>(ns, nt, zs1b, Wd, bd, wrec, out);
}

// Round 8
// 2979.891 us; speedup vs baseline: 1.0135x; 1.0135x over previous
//
#include <hip/hip_runtime.h>
#include <stdint.h>
#include <math.h>

// Problem constants
#define NN    50000       // N_NODES
#define NE    400000      // N_EDGES
#define NL    50000       // N_LINKS
#define TOT   12800000    // NN*256

#define JAX_PARTITIONABLE 1

struct K8 { uint32_t a[4]; uint32_t b[4]; };

// ---------------- Threefry-2x32 (20 rounds) ----------------
__host__ __device__ inline uint32_t rotl32(uint32_t x, int r){ return (x<<r)|(x>>(32-r)); }

__host__ __device__ inline void tf2x32(uint32_t k0, uint32_t k1, uint32_t x0, uint32_t x1,
                                       uint32_t &o0, uint32_t &o1) {
  uint32_t k2 = k0 ^ k1 ^ 0x1BD11BDAu;
  x0 += k0; x1 += k1;
#define TFR(r) { x0 += x1; x1 = rotl32(x1,(r)); x1 ^= x0; }
  TFR(13) TFR(15) TFR(26) TFR(6)
  x0 += k1; x1 += k2 + 1u;
  TFR(17) TFR(29) TFR(16) TFR(24)
  x0 += k2; x1 += k0 + 2u;
  TFR(13) TFR(15) TFR(26) TFR(6)
  x0 += k0; x1 += k1 + 3u;
  TFR(17) TFR(29) TFR(16) TFR(24)
  x0 += k1; x1 += k2 + 4u;
  TFR(13) TFR(15) TFR(26) TFR(6)
  x0 += k2; x1 += k0 + 5u;
#undef TFR
  o0 = x0; o1 = x1;
}

__device__ inline float u01(uint32_t b){
  return __uint_as_float((b>>9) | 0x3f800000u) - 1.0f;   // [1,2) - 1, exact
}

__device__ inline uint32_t jax_bits32(uint32_t ka, uint32_t kb, uint32_t i, uint32_t total){
#if JAX_PARTITIONABLE
  uint32_t o0,o1; tf2x32(ka,kb, 0u, i, o0,o1); return o0^o1;
#else
  uint32_t h = total>>1; uint32_t o0,o1;
  if (i < h){ tf2x32(ka,kb, i, i+h, o0,o1); return o0; }
  else      { tf2x32(ka,kb, i-h, i, o0,o1); return o1; }
#endif
}

__device__ inline double shflxor_d(double x, int m){
  union { double d; int i[2]; } u; u.d = x;
  u.i[0] = __shfl_xor(u.i[0], m, 64);
  u.i[1] = __shfl_xor(u.i[1], m, 64);
  return u.d;
}

// exact fp32 LIF step: v = fl(fl(v*0.5)+a); d = fl(v-0.2); s=(d>=0); v = s?d:v
__device__ inline bool lif32(float &v, float a){
  v = __fadd_rn(__fmul_rn(v, 0.5f), a);
  float d = __fsub_rn(v, 0.2f);
  bool s = (d >= 0.0f);
  v = s ? d : v;
  return s;
}

// force a value to live in a VGPR (defeats scalar-ization of uniform values)
#define FORCE_V(x) asm volatile("" : "+v"(x))

// wr if bit b of w set, else +0.0f — v_bfe_i32 + v_and_b32 (2 full-rate VALU ops)
__device__ inline float bitmaskf(uint32_t w, int b, float wr){
#if __has_builtin(__builtin_amdgcn_sbfe)
  int m = __builtin_amdgcn_sbfe((int)w, b, 1);       // 0x00000000 or 0xFFFFFFFF
#else
  int m = ((int)(w << (31-b))) >> 31;
#endif
  return __int_as_float(__float_as_int(wr) & m);
}

// ---------------- CSR build (by dst), deterministic edge order ----------------
__global__ __launch_bounds__(256) void k_hist(const int* __restrict__ dst, int* __restrict__ cnt){
  int e = blockIdx.x*256 + threadIdx.x;
  if (e < NE) atomicAdd(&cnt[dst[e]], 1);
}

__global__ __launch_bounds__(1024) void k_scan(const int* __restrict__ cnt,
    int* __restrict__ rp, int* __restrict__ cur){
  __shared__ int buf[1024];
  __shared__ int carry;
  int tid = threadIdx.x;
  if (tid==0) carry = 0;
  __syncthreads();
  for (int base=0; base<NN; base+=1024){
    int v = (base+tid < NN) ? cnt[base+tid] : 0;
    buf[tid] = v; __syncthreads();
    for (int off=1; off<1024; off<<=1){
      int t = (tid>=off) ? buf[tid-off] : 0;
      __syncthreads();
      buf[tid] += t;
      __syncthreads();
    }
    int excl = buf[tid] - v + carry;
    if (base+tid < NN){ rp[base+tid] = excl; cur[base+tid] = excl; }
    __syncthreads();
    if (tid==0) carry += buf[1023];
    __syncthreads();
  }
  if (tid==0) rp[NN] = NE;
}

__global__ __launch_bounds__(256) void k_scatter(const int* __restrict__ dst,
    int* __restrict__ cur, int* __restrict__ eidx){
  int e = blockIdx.x*256 + threadIdx.x;
  if (e < NE){ int p = atomicAdd(&cur[dst[e]], 1); eidx[p] = e; }
}

__global__ __launch_bounds__(256) void k_sortrow(const int* __restrict__ rp,
    int* __restrict__ eidx, const int* __restrict__ esrc, const float* __restrict__ ew,
    int* __restrict__ csrc, float* __restrict__ cw){
  int n = blockIdx.x*256 + threadIdx.x;
  if (n >= NN) return;
  int lo = rp[n], hi = rp[n+1];
  for (int a=lo+1; a<hi; a++){
    int k = eidx[a]; int b = a-1;
    while (b>=lo && eidx[b]>k){ eidx[b+1]=eidx[b]; b--; }
    eidx[b+1] = k;
  }
  for (int p=lo; p<hi; p++){ int e = eidx[p]; csrc[p] = esrc[e]; cw[p] = ew[e]; }
}

// Plane layouts (t innermost, 32B per (node,word)):
//   inpb/hs0b/zs0b : [node][w(4)][t(4)]   (NN*16 words)
//   hs1b           : [node][w(8)][t(4)]   (NN*32 words)
//   zs1b           : [node][w(2)][t(4)]   (NN*8  words)

// ---------------- Stage A: inp(t) = poisson(x, k1[t]) ----------------
__global__ __launch_bounds__(256) void k_pois_x(const float* __restrict__ x,
    uint64_t* __restrict__ bits, K8 K){
  int n = blockIdx.x, f = threadIdx.x;
  uint32_t i = (uint32_t)n*256u + (uint32_t)f;
  float xv = x[i];
  uint64_t pack[4];
  #pragma unroll
  for (int t=0;t<4;t++){
    bool b = (u01(jax_bits32(K.a[t],K.b[t], i, TOT)) <= xv);
    pack[t] = __ballot(b);
  }
  if ((f & 63)==0){
    uint64_t* dst = bits + ((size_t)n*4 + (f>>6))*4;
    #pragma unroll
    for (int t=0;t<4;t++) dst[t] = pack[t];
  }
}

// ---------------- Stage B: h0(t) fp32 gather (edge order) + poisson(h0,k2) ----------------
__global__ __launch_bounds__(256) void k_h0(const int* __restrict__ rp,
    const int* __restrict__ csrc, const float* __restrict__ cw,
    const uint64_t* __restrict__ inb, uint64_t* __restrict__ outb, K8 K){
  int n = blockIdx.x, f = threadIdx.x;
  int wi = f>>6, sh = f&63;
  int lo = rp[n], hi = rp[n+1];
  float a[4] = {0.f,0.f,0.f,0.f};
  for (int p=lo;p<hi;p++){
    int s = csrc[p]; float w = cw[p];
    const uint64_t* bp = inb + ((size_t)s*4 + wi)*4;   // 4 t-words, 32B contiguous
    uint64_t w0=bp[0], w1=bp[1], w2=bp[2], w3=bp[3];
    a[0] = __fadd_rn(a[0], ((w0>>sh)&1ull) ? w : 0.0f);
    a[1] = __fadd_rn(a[1], ((w1>>sh)&1ull) ? w : 0.0f);
    a[2] = __fadd_rn(a[2], ((w2>>sh)&1ull) ? w : 0.0f);
    a[3] = __fadd_rn(a[3], ((w3>>sh)&1ull) ? w : 0.0f);
  }
  uint32_t i = (uint32_t)n*256u + (uint32_t)f;
  uint64_t pack[4];
  #pragma unroll
  for (int t=0;t<4;t++){
    bool b = (u01(jax_bits32(K.a[t],K.b[t], i, TOT)) <= a[t]);
    pack[t] = __ballot(b);
  }
  if (sh==0){
    uint64_t* dst = outb + ((size_t)n*4 + wi)*4;
    #pragma unroll
    for (int t=0;t<4;t++) dst[t] = pack[t];
  }
}

// ---------------- Stage C: z0 = LIF_t(hs0 @ W1)  (K=256, M=256) ----------------
// LDS-staged weight tiles (32 k-rows x 256 cols = 32KB). Inner loop: 1 conflict-
// free ds_read_b32 + 16x(sbfe+and+fadd). Ascending-k order preserved (bit-exact).
__global__ __launch_bounds__(256) void k_z0(const uint64_t* __restrict__ inb,
    const float* __restrict__ W, uint64_t* __restrict__ outb){
  __shared__ __align__(16) float tile[32*256];    // 32KB
  int j = threadIdx.x;
  int n0 = blockIdx.x*4;
  const uint32_t* inw = (const uint32_t*)inb;
  float acc[4][4];                                // [t][i]
  #pragma unroll
  for (int t=0;t<4;t++)
    #pragma unroll
    for (int i=0;i<4;i++) acc[t][i] = 0.0f;

  for (int kt=0; kt<8; kt++){                     // K-tiles of 32 rows
    // stage: W rows [kt*32, kt*32+32) are 32KB contiguous
    const float4* gsrc = (const float4*)(W + (size_t)(kt*32)*256);
    float4* t4 = (float4*)tile;
    #pragma unroll
    for (int r=0;r<8;r++) t4[r*256 + j] = gsrc[r*256 + j];
    // spike half-words for this tile: word kw=kt/2, half=kt&1
    int kw = kt>>1, half = kt&1;
    uint32_t wv[4][4];                            // [i][t]
    #pragma unroll
    for (int i=0;i<4;i++)
      #pragma unroll
      for (int t=0;t<4;t++){
        wv[i][t] = inw[((((size_t)(n0+i))*4 + kw)*4 + t)*2 + half];
        FORCE_V(wv[i][t]);
      }
    __syncthreads();
    #pragma unroll 4
    for (int q=0;q<32;q++){
      float wr = tile[q*256 + j];
      #pragma unroll
      for (int i=0;i<4;i++)
        #pragma unroll
        for (int t=0;t<4;t++)
          acc[t][i] = __fadd_rn(acc[t][i], bitmaskf(wv[i][t], q, wr));
    }
    __syncthreads();
  }

  int wi = j>>6;
  #pragma unroll
  for (int i=0;i<4;i++){
    float v = 0.0f;
    uint64_t pack[4];
    #pragma unroll
    for (int t=0;t<4;t++){
      bool s = lif32(v, acc[t][i]);
      pack[t] = __ballot(s);
    }
    if ((j&63)==0){
      uint64_t* dst = outb + (((size_t)(n0+i))*4 + wi)*4;
      #pragma unroll
      for (int t=0;t<4;t++) dst[t] = pack[t];
    }
  }
}

// ---------------- Stage D: h1(t) gather over concat(zs0,hs0), LIF -> hs1 ----------------
__global__ __launch_bounds__(512) void k_h1(const int* __restrict__ rp,
    const int* __restrict__ csrc, const float* __restrict__ cw,
    const uint64_t* __restrict__ zs0b, const uint64_t* __restrict__ hs0b,
    uint64_t* __restrict__ hs1b){
  int n = blockIdx.x, f = threadIdx.x;           // f in [0,512)
  int wi = f>>6, sh = f&63;
  const uint64_t* plane = (wi<4) ? zs0b : hs0b;
  int wo = wi & 3;
  int lo = rp[n], hi = rp[n+1];
  float a[4] = {0.f,0.f,0.f,0.f};
  for (int p=lo;p<hi;p++){
    int s = csrc[p]; float w = cw[p];
    const uint64_t* bp = plane + ((size_t)s*4 + wo)*4;  // 32B contiguous
    uint64_t w0=bp[0], w1=bp[1], w2=bp[2], w3=bp[3];
    a[0] = __fadd_rn(a[0], ((w0>>sh)&1ull) ? w : 0.0f);
    a[1] = __fadd_rn(a[1], ((w1>>sh)&1ull) ? w : 0.0f);
    a[2] = __fadd_rn(a[2], ((w2>>sh)&1ull) ? w : 0.0f);
    a[3] = __fadd_rn(a[3], ((w3>>sh)&1ull) ? w : 0.0f);
  }
  float v = 0.0f;
  uint64_t pack[4];
  #pragma unroll
  for (int t=0;t<4;t++){
    bool s = lif32(v, a[t]);
    pack[t] = __ballot(s);
  }
  if (sh==0){
    uint64_t* dst = hs1b + ((size_t)n*8 + wi)*4;
    #pragma unroll
    for (int t=0;t<4;t++) dst[t] = pack[t];
  }
}

// ---------------- Stage E: z1 = LIF_t(hs1 @ W2)  (K=512, M=128) ----------------
// LDS-staged tiles (64 k-rows x 128 cols = 32KB).
__global__ __launch_bounds__(128) void k_z1(const uint64_t* __restrict__ inb,
    const float* __restrict__ W, uint64_t* __restrict__ outb){
  __shared__ __align__(16) float tile[64*128];    // 32KB
  int j = threadIdx.x;
  int n0 = blockIdx.x*4;
  float acc[4][4];
  #pragma unroll
  for (int t=0;t<4;t++)
    #pragma unroll
    for (int i=0;i<4;i++) acc[t][i] = 0.0f;

  for (int kt=0; kt<8; kt++){                     // K-tiles of 64 rows
    const float4* gsrc = (const float4*)(W + (size_t)(kt*64)*128);
    float4* t4 = (float4*)tile;
    #pragma unroll
    for (int r=0;r<16;r++) t4[r*128 + j] = gsrc[r*128 + j];
    // spike words for this tile: word kw = kt (full uint64)
    uint32_t wlo[4][4], whi[4][4];
    #pragma unroll
    for (int i=0;i<4;i++)
      #pragma unroll
      for (int t=0;t<4;t++){
        uint64_t w8 = inb[(((size_t)(n0+i))*8 + kt)*4 + t];
        wlo[i][t] = (uint32_t)w8;
        whi[i][t] = (uint32_t)(w8>>32);
        FORCE_V(wlo[i][t]); FORCE_V(whi[i][t]);
      }
    __syncthreads();
    #pragma unroll 4
    for (int q=0;q<32;q++){
      float wr = tile[q*128 + j];
      #pragma unroll
      for (int i=0;i<4;i++)
        #pragma unroll
        for (int t=0;t<4;t++)
          acc[t][i] = __fadd_rn(acc[t][i], bitmaskf(wlo[i][t], q, wr));
    }
    #pragma unroll 4
    for (int q=0;q<32;q++){
      float wr = tile[(32+q)*128 + j];
      #pragma unroll
      for (int i=0;i<4;i++)
        #pragma unroll
        for (int t=0;t<4;t++)
          acc[t][i] = __fadd_rn(acc[t][i], bitmaskf(whi[i][t], q, wr));
    }
    __syncthreads();
  }

  int wi = j>>6;  // 0 or 1
  #pragma unroll
  for (int i=0;i<4;i++){
    float v = 0.0f;
    uint64_t pack[4];
    #pragma unroll
    for (int t=0;t<4;t++){
      bool s = lif32(v, acc[t][i]);
      pack[t] = __ballot(s);
    }
    if ((j&63)==0){
      uint64_t* dst = outb + (((size_t)(n0+i))*2 + wi)*4;
      #pragma unroll
      for (int t=0;t<4;t++) dst[t] = pack[t];
    }
  }
}

// ---------------- Stage F: decoder + y + sigmoid ----------------
// block = 128 threads: wave0 = row i (ns), wave1 = row i+L (nt); j = DEC column
__global__ __launch_bounds__(128) void k_dec_y(const int* __restrict__ ns,
    const int* __restrict__ nt, const uint64_t* __restrict__ zs1b,
    const float* __restrict__ Wd, const float* __restrict__ bd,
    const float* __restrict__ wrec, float* __restrict__ out){
  int i = blockIdx.x;
  int tid = threadIdx.x;
  int row = tid>>6, j = tid&63;
  int node = row ? nt[i] : ns[i];
  float bdj = bd[j];
  double wrecj = (double)wrec[j];
  __shared__ uint64_t sw[2];

  // load this node's zs1 row: 2 k-groups x 4 t  (64B contiguous)
  uint32_t wlo[2][4], whi[2][4];
  const uint64_t* bp = zs1b + (size_t)node*8;
  #pragma unroll
  for (int g=0;g<2;g++)
    #pragma unroll
    for (int t=0;t<4;t++){
      uint64_t w8 = bp[g*4+t];
      wlo[g][t] = (uint32_t)w8;
      whi[g][t] = (uint32_t)(w8>>32);
      FORCE_V(wlo[g][t]); FORCE_V(whi[g][t]);
    }

  float acc[4] = {0.f,0.f,0.f,0.f};
  #pragma unroll
  for (int g=0;g<2;g++){
    #pragma unroll
    for (int h=0;h<2;h++){
      #pragma unroll
      for (int c=0;c<2;c++){
        float wr[16];
        #pragma unroll
        for (int q=0;q<16;q++) wr[q] = Wd[(size_t)(g*64+h*32+c*16+q)*64 + j];
        #pragma unroll
        for (int q=0;q<16;q++){
          int b = c*16+q;
          #pragma unroll
          for (int t=0;t<4;t++){
            uint32_t wv = h ? whi[g][t] : wlo[g][t];
            acc[t] = __fadd_rn(acc[t], bitmaskf(wv, b, wr[q]));
          }
        }
      }
    }
  }

  float v = 0.0f;
  double ysum = 0.0;
  #pragma unroll
  for (int t=0;t<4;t++){
    float a = __fadd_rn(acc[t], bdj);
    bool s = lif32(v, a);
    uint64_t bw = __ballot(s);
    if (j==0) sw[row] = bw;
    __syncthreads();
    uint64_t m = sw[0] & sw[1];
    __syncthreads();
    double term = ((m>>j)&1ull) ? wrecj : 0.0;
    #pragma unroll
    for (int off=1; off<64; off<<=1) term += shflxor_d(term, off);
    ysum += term;
  }
  if (tid==0) out[i] = (float)(1.0/(1.0 + exp(-0.25*ysum)));
}

// ---------------- Launcher ----------------
extern "C" void kernel_launch(void* const* d_in, const int* in_sizes, int n_in,
                              void* d_out, int out_size, void* d_ws, size_t ws_size,
                              hipStream_t stream) {
  const float* x    = (const float*)d_in[0];
  const float* W1   = (const float*)d_in[1];
  const float* W2   = (const float*)d_in[2];
  const float* Wd   = (const float*)d_in[3];
  const float* bd   = (const float*)d_in[4];
  const float* wrec = (const float*)d_in[5];
  const float* ew   = (const float*)d_in[6];
  const int* esrc   = (const int*)d_in[7];
  const int* edst   = (const int*)d_in[8];
  const int* ns     = (const int*)d_in[9];
  const int* nt     = (const int*)d_in[10];
  float* out = (float*)d_out;
  (void)in_sizes; (void)n_in; (void)out_size; (void)ws_size;

  // workspace layout (~41 MB)
  char* p = (char*)d_ws;
  uint64_t* inpb = (uint64_t*)p; p += (size_t)NN*16*8;
  uint64_t* hs0b = (uint64_t*)p; p += (size_t)NN*16*8;
  uint64_t* zs0b = (uint64_t*)p; p += (size_t)NN*16*8;
  uint64_t* hs1b = (uint64_t*)p; p += (size_t)NN*32*8;
  uint64_t* zs1b = (uint64_t*)p; p += (size_t)NN*8*8;
  int*   eidx = (int*)p;   p += (size_t)NE*4;
  int*   csrc = (int*)p;   p += (size_t)NE*4;
  float* cw   = (float*)p; p += (size_t)NE*4;
  int*   cnt  = (int*)p;   p += (size_t)(NN+2)*4;
  int*   rp   = (int*)p;   p += (size_t)(NN+2)*4;
  int*   cur  = (int*)p;   p += (size_t)(NN+2)*4;

  // host-side key chain: key=(0,42); kt=fold_in(key,t); k1,k2=split(kt)
  K8 K1, K2;
  for (int t=0;t<4;t++){
    uint32_t kt0,kt1;
    tf2x32(0u, 42u, 0u, (uint32_t)t, kt0, kt1);
#if JAX_PARTITIONABLE
    tf2x32(kt0, kt1, 0u, 0u, K1.a[t], K1.b[t]);
    tf2x32(kt0, kt1, 0u, 1u, K2.a[t], K2.b[t]);
#else
    uint32_t A0,B0,A1,B1;
    tf2x32(kt0, kt1, 0u, 2u, A0, B0);
    tf2x32(kt0, kt1, 1u, 3u, A1, B1);
    K1.a[t]=A0; K1.b[t]=A1; K2.a[t]=B0; K2.b[t]=B1;
#endif
  }

  // CSR build (deterministic via per-row sort by edge id)
  hipMemsetAsync(cnt, 0, (size_t)NN*4, stream);
  k_hist   <<<(NE+255)/256, 256, 0, stream>>>(edst, cnt);
  k_scan   <<<1, 1024, 0, stream>>>(cnt, rp, cur);
  k_scatter<<<(NE+255)/256, 256, 0, stream>>>(edst, cur, eidx);
  k_sortrow<<<(NN+255)/256, 256, 0, stream>>>(rp, eidx, esrc, ew, csrc, cw);

  // stage-major pipeline, all T=4 per kernel, LIF state in registers (fp32)
  k_pois_x<<<NN, 256, 0, stream>>>(x, inpb, K1);
  k_h0    <<<NN, 256, 0, stream>>>(rp, csrc, cw, inpb, hs0b, K2);
  k_z0    <<<NN/4, 256, 0, stream>>>(hs0b, W1, zs0b);
  k_h1    <<<NN, 512, 0, stream>>>(rp, csrc, cw, zs0b, hs0b, hs1b);
  k_z1    <<<NN/4, 128, 0, stream>>>(hs1b, W2, zs1b);
  k_dec_y <<<NL, 128, 0, stream>>>(ns, nt, zs1b, Wd, bd, wrec, out);
}

// Round 9
// 1739.495 us; speedup vs baseline: 1.7361x; 1.7131x over previous
//
#include <hip/hip_runtime.h>
#include <stdint.h>
#include <math.h>

// Problem constants
#define NN    50000       // N_NODES
#define NE    400000      // N_EDGES
#define NL    50000       // N_LINKS
#define TOT   12800000    // NN*256

#define JAX_PARTITIONABLE 1

struct K8 { uint32_t a[4]; uint32_t b[4]; };

// ---------------- Threefry-2x32 (20 rounds) ----------------
__host__ __device__ inline uint32_t rotl32(uint32_t x, int r){ return (x<<r)|(x>>(32-r)); }

__host__ __device__ inline void tf2x32(uint32_t k0, uint32_t k1, uint32_t x0, uint32_t x1,
                                       uint32_t &o0, uint32_t &o1) {
  uint32_t k2 = k0 ^ k1 ^ 0x1BD11BDAu;
  x0 += k0; x1 += k1;
#define TFR(r) { x0 += x1; x1 = rotl32(x1,(r)); x1 ^= x0; }
  TFR(13) TFR(15) TFR(26) TFR(6)
  x0 += k1; x1 += k2 + 1u;
  TFR(17) TFR(29) TFR(16) TFR(24)
  x0 += k2; x1 += k0 + 2u;
  TFR(13) TFR(15) TFR(26) TFR(6)
  x0 += k0; x1 += k1 + 3u;
  TFR(17) TFR(29) TFR(16) TFR(24)
  x0 += k1; x1 += k2 + 4u;
  TFR(13) TFR(15) TFR(26) TFR(6)
  x0 += k2; x1 += k0 + 5u;
#undef TFR
  o0 = x0; o1 = x1;
}

__device__ inline float u01(uint32_t b){
  return __uint_as_float((b>>9) | 0x3f800000u) - 1.0f;   // [1,2) - 1, exact
}

__device__ inline uint32_t jax_bits32(uint32_t ka, uint32_t kb, uint32_t i, uint32_t total){
#if JAX_PARTITIONABLE
  uint32_t o0,o1; tf2x32(ka,kb, 0u, i, o0,o1); return o0^o1;
#else
  uint32_t h = total>>1; uint32_t o0,o1;
  if (i < h){ tf2x32(ka,kb, i, i+h, o0,o1); return o0; }
  else      { tf2x32(ka,kb, i-h, i, o0,o1); return o1; }
#endif
}

__device__ inline double shflxor_d(double x, int m){
  union { double d; int i[2]; } u; u.d = x;
  u.i[0] = __shfl_xor(u.i[0], m, 64);
  u.i[1] = __shfl_xor(u.i[1], m, 64);
  return u.d;
}

// exact fp32 LIF step: v = fl(fl(v*0.5)+a); d = fl(v-0.2); s=(d>=0); v = s?d:v
__device__ inline bool lif32(float &v, float a){
  v = __fadd_rn(__fmul_rn(v, 0.5f), a);
  float d = __fsub_rn(v, 0.2f);
  bool s = (d >= 0.0f);
  v = s ? d : v;
  return s;
}

// force a value to live in a VGPR
#define FORCE_V(x) asm volatile("" : "+v"(x))

// wr if bit b of w set, else +0.0f — used in decoder (small)
__device__ inline float bitmaskf(uint32_t w, int b, float wr){
#if __has_builtin(__builtin_amdgcn_sbfe)
  int m = __builtin_amdgcn_sbfe((int)w, b, 1);
#else
  int m = ((int)(w << (31-b))) >> 31;
#endif
  return __int_as_float(__float_as_int(wr) & m);
}

// ---------------- CSR build (by dst), deterministic edge order ----------------
__global__ __launch_bounds__(256) void k_hist(const int* __restrict__ dst, int* __restrict__ cnt){
  int e = blockIdx.x*256 + threadIdx.x;
  if (e < NE) atomicAdd(&cnt[dst[e]], 1);
}

__global__ __launch_bounds__(1024) void k_scan(const int* __restrict__ cnt,
    int* __restrict__ rp, int* __restrict__ cur){
  __shared__ int buf[1024];
  __shared__ int carry;
  int tid = threadIdx.x;
  if (tid==0) carry = 0;
  __syncthreads();
  for (int base=0; base<NN; base+=1024){
    int v = (base+tid < NN) ? cnt[base+tid] : 0;
    buf[tid] = v; __syncthreads();
    for (int off=1; off<1024; off<<=1){
      int t = (tid>=off) ? buf[tid-off] : 0;
      __syncthreads();
      buf[tid] += t;
      __syncthreads();
    }
    int excl = buf[tid] - v + carry;
    if (base+tid < NN){ rp[base+tid] = excl; cur[base+tid] = excl; }
    __syncthreads();
    if (tid==0) carry += buf[1023];
    __syncthreads();
  }
  if (tid==0) rp[NN] = NE;
}

__global__ __launch_bounds__(256) void k_scatter(const int* __restrict__ dst,
    int* __restrict__ cur, int* __restrict__ eidx){
  int e = blockIdx.x*256 + threadIdx.x;
  if (e < NE){ int p = atomicAdd(&cur[dst[e]], 1); eidx[p] = e; }
}

__global__ __launch_bounds__(256) void k_sortrow(const int* __restrict__ rp,
    int* __restrict__ eidx, const int* __restrict__ esrc, const float* __restrict__ ew,
    int* __restrict__ csrc, float* __restrict__ cw){
  int n = blockIdx.x*256 + threadIdx.x;
  if (n >= NN) return;
  int lo = rp[n], hi = rp[n+1];
  for (int a=lo+1; a<hi; a++){
    int k = eidx[a]; int b = a-1;
    while (b>=lo && eidx[b]>k){ eidx[b+1]=eidx[b]; b--; }
    eidx[b+1] = k;
  }
  for (int p=lo; p<hi; p++){ int e = eidx[p]; csrc[p] = esrc[e]; cw[p] = ew[e]; }
}

// Plane layouts (t innermost, 32B per (node,word)):
//   inpb/hs0b/zs0b : [node][w(4)][t(4)]   (NN*16 words)
//   hs1b           : [node][w(8)][t(4)]   (NN*32 words)
//   zs1b           : [node][w(2)][t(4)]   (NN*8  words)

// ---------------- Stage A: inp(t) = poisson(x, k1[t]) ----------------
__global__ __launch_bounds__(256) void k_pois_x(const float* __restrict__ x,
    uint64_t* __restrict__ bits, K8 K){
  int n = blockIdx.x, f = threadIdx.x;
  uint32_t i = (uint32_t)n*256u + (uint32_t)f;
  float xv = x[i];
  uint64_t pack[4];
  #pragma unroll
  for (int t=0;t<4;t++){
    bool b = (u01(jax_bits32(K.a[t],K.b[t], i, TOT)) <= xv);
    pack[t] = __ballot(b);
  }
  if ((f & 63)==0){
    uint64_t* dst = bits + ((size_t)n*4 + (f>>6))*4;
    #pragma unroll
    for (int t=0;t<4;t++) dst[t] = pack[t];
  }
}

// ---------------- Stage B: h0(t) fp32 gather (edge order) + poisson(h0,k2) ----------------
__global__ __launch_bounds__(256) void k_h0(const int* __restrict__ rp,
    const int* __restrict__ csrc, const float* __restrict__ cw,
    const uint64_t* __restrict__ inb, uint64_t* __restrict__ outb, K8 K){
  int n = blockIdx.x, f = threadIdx.x;
  int wi = f>>6, sh = f&63;
  int lo = rp[n], hi = rp[n+1];
  float a[4] = {0.f,0.f,0.f,0.f};
  for (int p=lo;p<hi;p++){
    int s = csrc[p]; float w = cw[p];
    const uint64_t* bp = inb + ((size_t)s*4 + wi)*4;   // 4 t-words, 32B contiguous
    uint64_t w0=bp[0], w1=bp[1], w2=bp[2], w3=bp[3];
    a[0] = __fadd_rn(a[0], ((w0>>sh)&1ull) ? w : 0.0f);
    a[1] = __fadd_rn(a[1], ((w1>>sh)&1ull) ? w : 0.0f);
    a[2] = __fadd_rn(a[2], ((w2>>sh)&1ull) ? w : 0.0f);
    a[3] = __fadd_rn(a[3], ((w3>>sh)&1ull) ? w : 0.0f);
  }
  uint32_t i = (uint32_t)n*256u + (uint32_t)f;
  uint64_t pack[4];
  #pragma unroll
  for (int t=0;t<4;t++){
    bool b = (u01(jax_bits32(K.a[t],K.b[t], i, TOT)) <= a[t]);
    pack[t] = __ballot(b);
  }
  if (sh==0){
    uint64_t* dst = outb + ((size_t)n*4 + wi)*4;
    #pragma unroll
    for (int t=0;t<4;t++) dst[t] = pack[t];
  }
}

// ---------------- Stage C: z0 = LIF_t(hs0 @ W1)  (K=256, M=256) ----------------
// Per 64-k tile: expand the 16 block-uniform spike words into a 4KB LDS float
// tile [i][k][t] (spike 0.0/1.0), then inner loop = 1 coalesced wr load +
// 4 broadcast ds_read_b128 + 16 v_fma. fma(spike,wr,acc) is bit-exact vs the
// ascending-k fadd chain (spike in {0,1}).
__global__ __launch_bounds__(256) void k_z0(const uint64_t* __restrict__ inb,
    const float* __restrict__ W, uint64_t* __restrict__ outb){
  __shared__ __align__(16) float sp[4*64*4];     // [i][k][t] 4KB
  __shared__ uint64_t wbuf[16];                  // [i][t]
  int j = threadIdx.x;
  int n0 = blockIdx.x*4;
  float acc[4][4];                               // [t][i]
  #pragma unroll
  for (int t=0;t<4;t++)
    #pragma unroll
    for (int i=0;i<4;i++) acc[t][i] = 0.0f;

  for (int kt=0; kt<4; kt++){
    if (j < 16) wbuf[j] = inb[(((size_t)(n0+(j>>2)))*4 + kt)*4 + (j&3)];
    __syncthreads();
    {
      int i = j>>6, k = j&63;
      uint64_t w0=wbuf[i*4+0], w1=wbuf[i*4+1], w2=wbuf[i*4+2], w3=wbuf[i*4+3];
      float4 f;
      f.x = ((w0>>k)&1ull) ? 1.0f : 0.0f;
      f.y = ((w1>>k)&1ull) ? 1.0f : 0.0f;
      f.z = ((w2>>k)&1ull) ? 1.0f : 0.0f;
      f.w = ((w3>>k)&1ull) ? 1.0f : 0.0f;
      *(float4*)&sp[(i*64+k)*4] = f;
    }
    __syncthreads();
    const float* Wp = W + (size_t)(kt*64)*256 + j;
    #pragma unroll 4
    for (int q=0;q<64;q++){
      float wr = Wp[(size_t)q*256];
      float4 s0 = *(const float4*)&sp[(0*64+q)*4];
      float4 s1 = *(const float4*)&sp[(1*64+q)*4];
      float4 s2 = *(const float4*)&sp[(2*64+q)*4];
      float4 s3 = *(const float4*)&sp[(3*64+q)*4];
      acc[0][0]=__fmaf_rn(s0.x,wr,acc[0][0]); acc[1][0]=__fmaf_rn(s0.y,wr,acc[1][0]);
      acc[2][0]=__fmaf_rn(s0.z,wr,acc[2][0]); acc[3][0]=__fmaf_rn(s0.w,wr,acc[3][0]);
      acc[0][1]=__fmaf_rn(s1.x,wr,acc[0][1]); acc[1][1]=__fmaf_rn(s1.y,wr,acc[1][1]);
      acc[2][1]=__fmaf_rn(s1.z,wr,acc[2][1]); acc[3][1]=__fmaf_rn(s1.w,wr,acc[3][1]);
      acc[0][2]=__fmaf_rn(s2.x,wr,acc[0][2]); acc[1][2]=__fmaf_rn(s2.y,wr,acc[1][2]);
      acc[2][2]=__fmaf_rn(s2.z,wr,acc[2][2]); acc[3][2]=__fmaf_rn(s2.w,wr,acc[3][2]);
      acc[0][3]=__fmaf_rn(s3.x,wr,acc[0][3]); acc[1][3]=__fmaf_rn(s3.y,wr,acc[1][3]);
      acc[2][3]=__fmaf_rn(s3.z,wr,acc[2][3]); acc[3][3]=__fmaf_rn(s3.w,wr,acc[3][3]);
    }
    __syncthreads();
  }

  int wi = j>>6;
  #pragma unroll
  for (int i=0;i<4;i++){
    float v = 0.0f;
    uint64_t pack[4];
    #pragma unroll
    for (int t=0;t<4;t++){
      bool s = lif32(v, acc[t][i]);
      pack[t] = __ballot(s);
    }
    if ((j&63)==0){
      uint64_t* dst = outb + (((size_t)(n0+i))*4 + wi)*4;
      #pragma unroll
      for (int t=0;t<4;t++) dst[t] = pack[t];
    }
  }
}

// ---------------- Stage D: h1(t) gather over concat(zs0,hs0), LIF -> hs1 ----------------
__global__ __launch_bounds__(512) void k_h1(const int* __restrict__ rp,
    const int* __restrict__ csrc, const float* __restrict__ cw,
    const uint64_t* __restrict__ zs0b, const uint64_t* __restrict__ hs0b,
    uint64_t* __restrict__ hs1b){
  int n = blockIdx.x, f = threadIdx.x;           // f in [0,512)
  int wi = f>>6, sh = f&63;
  const uint64_t* plane = (wi<4) ? zs0b : hs0b;
  int wo = wi & 3;
  int lo = rp[n], hi = rp[n+1];
  float a[4] = {0.f,0.f,0.f,0.f};
  for (int p=lo;p<hi;p++){
    int s = csrc[p]; float w = cw[p];
    const uint64_t* bp = plane + ((size_t)s*4 + wo)*4;  // 32B contiguous
    uint64_t w0=bp[0], w1=bp[1], w2=bp[2], w3=bp[3];
    a[0] = __fadd_rn(a[0], ((w0>>sh)&1ull) ? w : 0.0f);
    a[1] = __fadd_rn(a[1], ((w1>>sh)&1ull) ? w : 0.0f);
    a[2] = __fadd_rn(a[2], ((w2>>sh)&1ull) ? w : 0.0f);
    a[3] = __fadd_rn(a[3], ((w3>>sh)&1ull) ? w : 0.0f);
  }
  float v = 0.0f;
  uint64_t pack[4];
  #pragma unroll
  for (int t=0;t<4;t++){
    bool s = lif32(v, a[t]);
    pack[t] = __ballot(s);
  }
  if (sh==0){
    uint64_t* dst = hs1b + ((size_t)n*8 + wi)*4;
    #pragma unroll
    for (int t=0;t<4;t++) dst[t] = pack[t];
  }
}

// ---------------- Stage E: z1 = LIF_t(hs1 @ W2)  (K=512, M=128) ----------------
__global__ __launch_bounds__(128) void k_z1(const uint64_t* __restrict__ inb,
    const float* __restrict__ W, uint64_t* __restrict__ outb){
  __shared__ __align__(16) float sp[4*64*4];     // [i][k][t] 4KB
  __shared__ uint64_t wbuf[16];                  // [i][t]
  int j = threadIdx.x;
  int n0 = blockIdx.x*4;
  float acc[4][4];
  #pragma unroll
  for (int t=0;t<4;t++)
    #pragma unroll
    for (int i=0;i<4;i++) acc[t][i] = 0.0f;

  for (int kt=0; kt<8; kt++){
    if (j < 16) wbuf[j] = inb[(((size_t)(n0+(j>>2)))*8 + kt)*4 + (j&3)];
    __syncthreads();
    #pragma unroll
    for (int rep=0; rep<2; rep++){
      int idx = rep*128 + j;
      int i = idx>>6, k = idx&63;
      uint64_t w0=wbuf[i*4+0], w1=wbuf[i*4+1], w2=wbuf[i*4+2], w3=wbuf[i*4+3];
      float4 f;
      f.x = ((w0>>k)&1ull) ? 1.0f : 0.0f;
      f.y = ((w1>>k)&1ull) ? 1.0f : 0.0f;
      f.z = ((w2>>k)&1ull) ? 1.0f : 0.0f;
      f.w = ((w3>>k)&1ull) ? 1.0f : 0.0f;
      *(float4*)&sp[(i*64+k)*4] = f;
    }
    __syncthreads();
    const float* Wp = W + (size_t)(kt*64)*128 + j;
    #pragma unroll 4
    for (int q=0;q<64;q++){
      float wr = Wp[(size_t)q*128];
      float4 s0 = *(const float4*)&sp[(0*64+q)*4];
      float4 s1 = *(const float4*)&sp[(1*64+q)*4];
      float4 s2 = *(const float4*)&sp[(2*64+q)*4];
      float4 s3 = *(const float4*)&sp[(3*64+q)*4];
      acc[0][0]=__fmaf_rn(s0.x,wr,acc[0][0]); acc[1][0]=__fmaf_rn(s0.y,wr,acc[1][0]);
      acc[2][0]=__fmaf_rn(s0.z,wr,acc[2][0]); acc[3][0]=__fmaf_rn(s0.w,wr,acc[3][0]);
      acc[0][1]=__fmaf_rn(s1.x,wr,acc[0][1]); acc[1][1]=__fmaf_rn(s1.y,wr,acc[1][1]);
      acc[2][1]=__fmaf_rn(s1.z,wr,acc[2][1]); acc[3][1]=__fmaf_rn(s1.w,wr,acc[3][1]);
      acc[0][2]=__fmaf_rn(s2.x,wr,acc[0][2]); acc[1][2]=__fmaf_rn(s2.y,wr,acc[1][2]);
      acc[2][2]=__fmaf_rn(s2.z,wr,acc[2][2]); acc[3][2]=__fmaf_rn(s2.w,wr,acc[3][2]);
      acc[0][3]=__fmaf_rn(s3.x,wr,acc[0][3]); acc[1][3]=__fmaf_rn(s3.y,wr,acc[1][3]);
      acc[2][3]=__fmaf_rn(s3.z,wr,acc[2][3]); acc[3][3]=__fmaf_rn(s3.w,wr,acc[3][3]);
    }
    __syncthreads();
  }

  int wi = j>>6;  // 0 or 1
  #pragma unroll
  for (int i=0;i<4;i++){
    float v = 0.0f;
    uint64_t pack[4];
    #pragma unroll
    for (int t=0;t<4;t++){
      bool s = lif32(v, acc[t][i]);
      pack[t] = __ballot(s);
    }
    if ((j&63)==0){
      uint64_t* dst = outb + (((size_t)(n0+i))*2 + wi)*4;
      #pragma unroll
      for (int t=0;t<4;t++) dst[t] = pack[t];
    }
  }
}

// ---------------- Stage F: decoder + y + sigmoid ----------------
__global__ __launch_bounds__(128) void k_dec_y(const int* __restrict__ ns,
    const int* __restrict__ nt, const uint64_t* __restrict__ zs1b,
    const float* __restrict__ Wd, const float* __restrict__ bd,
    const float* __restrict__ wrec, float* __restrict__ out){
  int i = blockIdx.x;
  int tid = threadIdx.x;
  int row = tid>>6, j = tid&63;
  int node = row ? nt[i] : ns[i];
  float bdj = bd[j];
  double wrecj = (double)wrec[j];
  __shared__ uint64_t sw[2];

  uint32_t wlo[2][4], whi[2][4];
  const uint64_t* bp = zs1b + (size_t)node*8;
  #pragma unroll
  for (int g=0;g<2;g++)
    #pragma unroll
    for (int t=0;t<4;t++){
      uint64_t w8 = bp[g*4+t];
      wlo[g][t] = (uint32_t)w8;
      whi[g][t] = (uint32_t)(w8>>32);
      FORCE_V(wlo[g][t]); FORCE_V(whi[g][t]);
    }

  float acc[4] = {0.f,0.f,0.f,0.f};
  #pragma unroll
  for (int g=0;g<2;g++){
    #pragma unroll
    for (int h=0;h<2;h++){
      #pragma unroll
      for (int c=0;c<2;c++){
        float wr[16];
        #pragma unroll
        for (int q=0;q<16;q++) wr[q] = Wd[(size_t)(g*64+h*32+c*16+q)*64 + j];
        #pragma unroll
        for (int q=0;q<16;q++){
          int b = c*16+q;
          #pragma unroll
          for (int t=0;t<4;t++){
            uint32_t wv = h ? whi[g][t] : wlo[g][t];
            acc[t] = __fadd_rn(acc[t], bitmaskf(wv, b, wr[q]));
          }
        }
      }
    }
  }

  float v = 0.0f;
  double ysum = 0.0;
  #pragma unroll
  for (int t=0;t<4;t++){
    float a = __fadd_rn(acc[t], bdj);
    bool s = lif32(v, a);
    uint64_t bw = __ballot(s);
    if (j==0) sw[row] = bw;
    __syncthreads();
    uint64_t m = sw[0] & sw[1];
    __syncthreads();
    double term = ((m>>j)&1ull) ? wrecj : 0.0;
    #pragma unroll
    for (int off=1; off<64; off<<=1) term += shflxor_d(term, off);
    ysum += term;
  }
  if (tid==0) out[i] = (float)(1.0/(1.0 + exp(-0.25*ysum)));
}

// ---------------- Launcher ----------------
extern "C" void kernel_launch(void* const* d_in, const int* in_sizes, int n_in,
                              void* d_out, int out_size, void* d_ws, size_t ws_size,
                              hipStream_t stream) {
  const float* x    = (const float*)d_in[0];
  const float* W1   = (const float*)d_in[1];
  const float* W2   = (const float*)d_in[2];
  const float* Wd   = (const float*)d_in[3];
  const float* bd   = (const float*)d_in[4];
  const float* wrec = (const float*)d_in[5];
  const float* ew   = (const float*)d_in[6];
  const int* esrc   = (const int*)d_in[7];
  const int* edst   = (const int*)d_in[8];
  const int* ns     = (const int*)d_in[9];
  const int* nt     = (const int*)d_in[10];
  float* out = (float*)d_out;
  (void)in_sizes; (void)n_in; (void)out_size; (void)ws_size;

  // workspace layout (~41 MB)
  char* p = (char*)d_ws;
  uint64_t* inpb = (uint64_t*)p; p += (size_t)NN*16*8;
  uint64_t* hs0b = (uint64_t*)p; p += (size_t)NN*16*8;
  uint64_t* zs0b = (uint64_t*)p; p += (size_t)NN*16*8;
  uint64_t* hs1b = (uint64_t*)p; p += (size_t)NN*32*8;
  uint64_t* zs1b = (uint64_t*)p; p += (size_t)NN*8*8;
  int*   eidx = (int*)p;   p += (size_t)NE*4;
  int*   csrc = (int*)p;   p += (size_t)NE*4;
  float* cw   = (float*)p; p += (size_t)NE*4;
  int*   cnt  = (int*)p;   p += (size_t)(NN+2)*4;
  int*   rp   = (int*)p;   p += (size_t)(NN+2)*4;
  int*   cur  = (int*)p;   p += (size_t)(NN+2)*4;

  // host-side key chain: key=(0,42); kt=fold_in(key,t); k1,k2=split(kt)
  K8 K1, K2;
  for (int t=0;t<4;t++){
    uint32_t kt0,kt1;
    tf2x32(0u, 42u, 0u, (uint32_t)t, kt0, kt1);
#if JAX_PARTITIONABLE
    tf2x32(kt0, kt1, 0u, 0u, K1.a[t], K1.b[t]);
    tf2x32(kt0, kt1, 0u, 1u, K2.a[t], K2.b[t]);
#else
    uint32_t A0,B0,A1,B1;
    tf2x32(kt0, kt1, 0u, 2u, A0, B0);
    tf2x32(kt0, kt1, 1u, 3u, A1, B1);
    K1.a[t]=A0; K1.b[t]=A1; K2.a[t]=B0; K2.b[t]=B1;
#endif
  }

  // CSR build (deterministic via per-row sort by edge id)
  hipMemsetAsync(cnt, 0, (size_t)NN*4, stream);
  k_hist   <<<(NE+255)/256, 256, 0, stream>>>(edst, cnt);
  k_scan   <<<1, 1024, 0, stream>>>(cnt, rp, cur);
  k_scatter<<<(NE+255)/256, 256, 0, stream>>>(edst, cur, eidx);
  k_sortrow<<<(NN+255)/256, 256, 0, stream>>>(rp, eidx, esrc, ew, csrc, cw);

  // stage-major pipeline, all T=4 per kernel, LIF state in registers (fp32)
  k_pois_x<<<NN, 256, 0, stream>>>(x, inpb, K1);
  k_h0    <<<NN, 256, 0, stream>>>(rp, csrc, cw, inpb, hs0b, K2);
  k_z0    <<<NN/4, 256, 0, stream>>>(hs0b, W1, zs0b);
  k_h1    <<<NN, 512, 0, stream>>>(rp, csrc, cw, zs0b, hs0b, hs1b);
  k_z1    <<<NN/4, 128, 0, stream>>>(hs1b, W2, zs1b);
  k_dec_y <<<NL, 128, 0, stream>>>(ns, nt, zs1b, Wd, bd, wrec, out);
}

// Round 10
// 1633.439 us; speedup vs baseline: 1.8488x; 1.0649x over previous
//
#include <hip/hip_runtime.h>
#include <stdint.h>
#include <math.h>

// Problem constants
#define NN    50000       // N_NODES
#define NE    400000      // N_EDGES
#define NL    50000       // N_LINKS
#define TOT   12800000    // NN*256

#define JAX_PARTITIONABLE 1

struct K8 { uint32_t a[4]; uint32_t b[4]; };

// ---------------- Threefry-2x32 (20 rounds) ----------------
__host__ __device__ inline uint32_t rotl32(uint32_t x, int r){ return (x<<r)|(x>>(32-r)); }

__host__ __device__ inline void tf2x32(uint32_t k0, uint32_t k1, uint32_t x0, uint32_t x1,
                                       uint32_t &o0, uint32_t &o1) {
  uint32_t k2 = k0 ^ k1 ^ 0x1BD11BDAu;
  x0 += k0; x1 += k1;
#define TFR(r) { x0 += x1; x1 = rotl32(x1,(r)); x1 ^= x0; }
  TFR(13) TFR(15) TFR(26) TFR(6)
  x0 += k1; x1 += k2 + 1u;
  TFR(17) TFR(29) TFR(16) TFR(24)
  x0 += k2; x1 += k0 + 2u;
  TFR(13) TFR(15) TFR(26) TFR(6)
  x0 += k0; x1 += k1 + 3u;
  TFR(17) TFR(29) TFR(16) TFR(24)
  x0 += k1; x1 += k2 + 4u;
  TFR(13) TFR(15) TFR(26) TFR(6)
  x0 += k2; x1 += k0 + 5u;
#undef TFR
  o0 = x0; o1 = x1;
}

__device__ inline float u01(uint32_t b){
  return __uint_as_float((b>>9) | 0x3f800000u) - 1.0f;   // [1,2) - 1, exact
}

__device__ inline uint32_t jax_bits32(uint32_t ka, uint32_t kb, uint32_t i, uint32_t total){
#if JAX_PARTITIONABLE
  uint32_t o0,o1; tf2x32(ka,kb, 0u, i, o0,o1); return o0^o1;
#else
  uint32_t h = total>>1; uint32_t o0,o1;
  if (i < h){ tf2x32(ka,kb, i, i+h, o0,o1); return o0; }
  else      { tf2x32(ka,kb, i-h, i, o0,o1); return o1; }
#endif
}

__device__ inline double shflxor_d(double x, int m){
  union { double d; int i[2]; } u; u.d = x;
  u.i[0] = __shfl_xor(u.i[0], m, 64);
  u.i[1] = __shfl_xor(u.i[1], m, 64);
  return u.d;
}

// exact fp32 LIF step: v = fl(fl(v*0.5)+a); d = fl(v-0.2); s=(d>=0); v = s?d:v
__device__ inline bool lif32(float &v, float a){
  v = __fadd_rn(__fmul_rn(v, 0.5f), a);
  float d = __fsub_rn(v, 0.2f);
  bool s = (d >= 0.0f);
  v = s ? d : v;
  return s;
}

// force a value to live in a VGPR
#define FORCE_V(x) asm volatile("" : "+v"(x))

// wr if bit b of w set, else +0.0f — used in decoder (small)
__device__ inline float bitmaskf(uint32_t w, int b, float wr){
#if __has_builtin(__builtin_amdgcn_sbfe)
  int m = __builtin_amdgcn_sbfe((int)w, b, 1);
#else
  int m = ((int)(w << (31-b))) >> 31;
#endif
  return __int_as_float(__float_as_int(wr) & m);
}

// ---------------- CSR build (by dst), deterministic edge order ----------------
__global__ __launch_bounds__(256) void k_hist(const int* __restrict__ dst, int* __restrict__ cnt){
  int e = blockIdx.x*256 + threadIdx.x;
  if (e < NE) atomicAdd(&cnt[dst[e]], 1);
}

__global__ __launch_bounds__(1024) void k_scan(const int* __restrict__ cnt,
    int* __restrict__ rp, int* __restrict__ cur){
  __shared__ int buf[1024];
  __shared__ int carry;
  int tid = threadIdx.x;
  if (tid==0) carry = 0;
  __syncthreads();
  for (int base=0; base<NN; base+=1024){
    int v = (base+tid < NN) ? cnt[base+tid] : 0;
    buf[tid] = v; __syncthreads();
    for (int off=1; off<1024; off<<=1){
      int t = (tid>=off) ? buf[tid-off] : 0;
      __syncthreads();
      buf[tid] += t;
      __syncthreads();
    }
    int excl = buf[tid] - v + carry;
    if (base+tid < NN){ rp[base+tid] = excl; cur[base+tid] = excl; }
    __syncthreads();
    if (tid==0) carry += buf[1023];
    __syncthreads();
  }
  if (tid==0) rp[NN] = NE;
}

__global__ __launch_bounds__(256) void k_scatter(const int* __restrict__ dst,
    int* __restrict__ cur, int* __restrict__ eidx){
  int e = blockIdx.x*256 + threadIdx.x;
  if (e < NE){ int p = atomicAdd(&cur[dst[e]], 1); eidx[p] = e; }
}

__global__ __launch_bounds__(256) void k_sortrow(const int* __restrict__ rp,
    int* __restrict__ eidx, const int* __restrict__ esrc, const float* __restrict__ ew,
    int* __restrict__ csrc, float* __restrict__ cw){
  int n = blockIdx.x*256 + threadIdx.x;
  if (n >= NN) return;
  int lo = rp[n], hi = rp[n+1];
  for (int a=lo+1; a<hi; a++){
    int k = eidx[a]; int b = a-1;
    while (b>=lo && eidx[b]>k){ eidx[b+1]=eidx[b]; b--; }
    eidx[b+1] = k;
  }
  for (int p=lo; p<hi; p++){ int e = eidx[p]; csrc[p] = esrc[e]; cw[p] = ew[e]; }
}

// Plane layouts (t innermost, 32B per (node,word)):
//   inpb/hs0b/zs0b : [node][w(4)][t(4)]   (NN*16 words)
//   hs1b           : [node][w(8)][t(4)]   (NN*32 words)
//   zs1b           : [node][w(2)][t(4)]   (NN*8  words)

// ---------------- Stage A: inp(t) = poisson(x, k1[t]) ----------------
__global__ __launch_bounds__(256) void k_pois_x(const float* __restrict__ x,
    uint64_t* __restrict__ bits, K8 K){
  int n = blockIdx.x, f = threadIdx.x;
  uint32_t i = (uint32_t)n*256u + (uint32_t)f;
  float xv = x[i];
  uint64_t pack[4];
  #pragma unroll
  for (int t=0;t<4;t++){
    bool b = (u01(jax_bits32(K.a[t],K.b[t], i, TOT)) <= xv);
    pack[t] = __ballot(b);
  }
  if ((f & 63)==0){
    uint64_t* dst = bits + ((size_t)n*4 + (f>>6))*4;
    #pragma unroll
    for (int t=0;t<4;t++) dst[t] = pack[t];
  }
}

// ---------------- Stage B: h0(t) fp32 gather (edge order) + poisson(h0,k2) ----------------
__global__ __launch_bounds__(256) void k_h0(const int* __restrict__ rp,
    const int* __restrict__ csrc, const float* __restrict__ cw,
    const uint64_t* __restrict__ inb, uint64_t* __restrict__ outb, K8 K){
  int n = blockIdx.x, f = threadIdx.x;
  int wi = f>>6, sh = f&63;
  int lo = rp[n], hi = rp[n+1];
  float a[4] = {0.f,0.f,0.f,0.f};
  for (int p=lo;p<hi;p++){
    int s = csrc[p]; float w = cw[p];
    const uint64_t* bp = inb + ((size_t)s*4 + wi)*4;   // 4 t-words, 32B contiguous
    uint64_t w0=bp[0], w1=bp[1], w2=bp[2], w3=bp[3];
    a[0] = __fadd_rn(a[0], ((w0>>sh)&1ull) ? w : 0.0f);
    a[1] = __fadd_rn(a[1], ((w1>>sh)&1ull) ? w : 0.0f);
    a[2] = __fadd_rn(a[2], ((w2>>sh)&1ull) ? w : 0.0f);
    a[3] = __fadd_rn(a[3], ((w3>>sh)&1ull) ? w : 0.0f);
  }
  uint32_t i = (uint32_t)n*256u + (uint32_t)f;
  uint64_t pack[4];
  #pragma unroll
  for (int t=0;t<4;t++){
    bool b = (u01(jax_bits32(K.a[t],K.b[t], i, TOT)) <= a[t]);
    pack[t] = __ballot(b);
  }
  if (sh==0){
    uint64_t* dst = outb + ((size_t)n*4 + wi)*4;
    #pragma unroll
    for (int t=0;t<4;t++) dst[t] = pack[t];
  }
}

// ---------------- Stage C: z0 = LIF_t(hs0 @ W1)  (K=256, M=256) ----------------
// 8 nodes/block, 2 cols/thread. Per q: 2 coalesced wr loads + 4 broadcast
// ds_read_b128 + 32 v_fma (ds:fma = 1:8). fma(spike{0,1},wr,acc) bit-exact.
__global__ __launch_bounds__(256) void k_z0(const uint64_t* __restrict__ inb,
    const float* __restrict__ W, uint64_t* __restrict__ outb){
  __shared__ __align__(16) float sp[8*64*4];     // [i(8)][k(64)][t(4)] 8KB
  int tid = threadIdx.x;
  int wave = tid>>6, lane = tid&63;
  int g = wave>>1;                                // node group (0,1)
  int ch = wave&1;                                // column half (0,1)
  int colBase = ch*128;
  int n0 = blockIdx.x*8;
  float acc[4][4][2];                             // [t][i][c]
  #pragma unroll
  for (int t=0;t<4;t++)
    #pragma unroll
    for (int i=0;i<4;i++){ acc[t][i][0]=0.0f; acc[t][i][1]=0.0f; }

  for (int kt=0; kt<4; kt++){
    // expand spikes: 512 slots (i,k), 2 per thread; 32B L1-hot load each
    #pragma unroll
    for (int rep=0; rep<2; rep++){
      int idx = rep*256 + tid;
      int i = idx>>6, k = idx&63;
      const uint64_t* bp = inb + (((size_t)(n0+i))*4 + kt)*4;
      uint64_t w0=bp[0], w1=bp[1], w2=bp[2], w3=bp[3];
      float4 f;
      f.x = ((w0>>k)&1ull) ? 1.0f : 0.0f;
      f.y = ((w1>>k)&1ull) ? 1.0f : 0.0f;
      f.z = ((w2>>k)&1ull) ? 1.0f : 0.0f;
      f.w = ((w3>>k)&1ull) ? 1.0f : 0.0f;
      *(float4*)&sp[(i*64+k)*4] = f;
    }
    __syncthreads();
    const float* Wrow = W + (size_t)(kt*64)*256 + colBase + lane;
    #pragma unroll 4
    for (int q=0;q<64;q++){
      float wr0 = Wrow[(size_t)q*256];
      float wr1 = Wrow[(size_t)q*256 + 64];
      float4 s0 = *(const float4*)&sp[((g*4+0)*64+q)*4];
      float4 s1 = *(const float4*)&sp[((g*4+1)*64+q)*4];
      float4 s2 = *(const float4*)&sp[((g*4+2)*64+q)*4];
      float4 s3 = *(const float4*)&sp[((g*4+3)*64+q)*4];
      acc[0][0][0]=__fmaf_rn(s0.x,wr0,acc[0][0][0]); acc[0][0][1]=__fmaf_rn(s0.x,wr1,acc[0][0][1]);
      acc[1][0][0]=__fmaf_rn(s0.y,wr0,acc[1][0][0]); acc[1][0][1]=__fmaf_rn(s0.y,wr1,acc[1][0][1]);
      acc[2][0][0]=__fmaf_rn(s0.z,wr0,acc[2][0][0]); acc[2][0][1]=__fmaf_rn(s0.z,wr1,acc[2][0][1]);
      acc[3][0][0]=__fmaf_rn(s0.w,wr0,acc[3][0][0]); acc[3][0][1]=__fmaf_rn(s0.w,wr1,acc[3][0][1]);
      acc[0][1][0]=__fmaf_rn(s1.x,wr0,acc[0][1][0]); acc[0][1][1]=__fmaf_rn(s1.x,wr1,acc[0][1][1]);
      acc[1][1][0]=__fmaf_rn(s1.y,wr0,acc[1][1][0]); acc[1][1][1]=__fmaf_rn(s1.y,wr1,acc[1][1][1]);
      acc[2][1][0]=__fmaf_rn(s1.z,wr0,acc[2][1][0]); acc[2][1][1]=__fmaf_rn(s1.z,wr1,acc[2][1][1]);
      acc[3][1][0]=__fmaf_rn(s1.w,wr0,acc[3][1][0]); acc[3][1][1]=__fmaf_rn(s1.w,wr1,acc[3][1][1]);
      acc[0][2][0]=__fmaf_rn(s2.x,wr0,acc[0][2][0]); acc[0][2][1]=__fmaf_rn(s2.x,wr1,acc[0][2][1]);
      acc[1][2][0]=__fmaf_rn(s2.y,wr0,acc[1][2][0]); acc[1][2][1]=__fmaf_rn(s2.y,wr1,acc[1][2][1]);
      acc[2][2][0]=__fmaf_rn(s2.z,wr0,acc[2][2][0]); acc[2][2][1]=__fmaf_rn(s2.z,wr1,acc[2][2][1]);
      acc[3][2][0]=__fmaf_rn(s2.w,wr0,acc[3][2][0]); acc[3][2][1]=__fmaf_rn(s2.w,wr1,acc[3][2][1]);
      acc[0][3][0]=__fmaf_rn(s3.x,wr0,acc[0][3][0]); acc[0][3][1]=__fmaf_rn(s3.x,wr1,acc[0][3][1]);
      acc[1][3][0]=__fmaf_rn(s3.y,wr0,acc[1][3][0]); acc[1][3][1]=__fmaf_rn(s3.y,wr1,acc[1][3][1]);
      acc[2][3][0]=__fmaf_rn(s3.z,wr0,acc[2][3][0]); acc[2][3][1]=__fmaf_rn(s3.z,wr1,acc[2][3][1]);
      acc[3][3][0]=__fmaf_rn(s3.w,wr0,acc[3][3][0]); acc[3][3][1]=__fmaf_rn(s3.w,wr1,acc[3][3][1]);
    }
    __syncthreads();
  }

  #pragma unroll
  for (int i=0;i<4;i++){
    int node = n0 + g*4 + i;
    float v0 = 0.0f, v1 = 0.0f;
    uint64_t p0[4], p1[4];
    #pragma unroll
    for (int t=0;t<4;t++){
      bool s0 = lif32(v0, acc[t][i][0]);
      bool s1 = lif32(v1, acc[t][i][1]);
      p0[t] = __ballot(s0);
      p1[t] = __ballot(s1);
    }
    if (lane==0){
      uint64_t* d0 = outb + ((size_t)node*4 + ch*2    )*4;
      uint64_t* d1 = outb + ((size_t)node*4 + ch*2 + 1)*4;
      #pragma unroll
      for (int t=0;t<4;t++){ d0[t]=p0[t]; d1[t]=p1[t]; }
    }
  }
}

// ---------------- Stage D: h1(t) gather over concat(zs0,hs0), LIF -> hs1 ----------------
__global__ __launch_bounds__(512) void k_h1(const int* __restrict__ rp,
    const int* __restrict__ csrc, const float* __restrict__ cw,
    const uint64_t* __restrict__ zs0b, const uint64_t* __restrict__ hs0b,
    uint64_t* __restrict__ hs1b){
  int n = blockIdx.x, f = threadIdx.x;           // f in [0,512)
  int wi = f>>6, sh = f&63;
  const uint64_t* plane = (wi<4) ? zs0b : hs0b;
  int wo = wi & 3;
  int lo = rp[n], hi = rp[n+1];
  float a[4] = {0.f,0.f,0.f,0.f};
  for (int p=lo;p<hi;p++){
    int s = csrc[p]; float w = cw[p];
    const uint64_t* bp = plane + ((size_t)s*4 + wo)*4;  // 32B contiguous
    uint64_t w0=bp[0], w1=bp[1], w2=bp[2], w3=bp[3];
    a[0] = __fadd_rn(a[0], ((w0>>sh)&1ull) ? w : 0.0f);
    a[1] = __fadd_rn(a[1], ((w1>>sh)&1ull) ? w : 0.0f);
    a[2] = __fadd_rn(a[2], ((w2>>sh)&1ull) ? w : 0.0f);
    a[3] = __fadd_rn(a[3], ((w3>>sh)&1ull) ? w : 0.0f);
  }
  float v = 0.0f;
  uint64_t pack[4];
  #pragma unroll
  for (int t=0;t<4;t++){
    bool s = lif32(v, a[t]);
    pack[t] = __ballot(s);
  }
  if (sh==0){
    uint64_t* dst = hs1b + ((size_t)n*8 + wi)*4;
    #pragma unroll
    for (int t=0;t<4;t++) dst[t] = pack[t];
  }
}

// ---------------- Stage E: z1 = LIF_t(hs1 @ W2)  (K=512, M=128) ----------------
// 8 nodes/block (one group per wave), 2 cols/thread.
__global__ __launch_bounds__(128) void k_z1(const uint64_t* __restrict__ inb,
    const float* __restrict__ W, uint64_t* __restrict__ outb){
  __shared__ __align__(16) float sp[8*64*4];     // [i(8)][k(64)][t(4)] 8KB
  int tid = threadIdx.x;
  int g = tid>>6, lane = tid&63;                  // wave = node group
  int n0 = blockIdx.x*8;
  float acc[4][4][2];                             // [t][i][c]
  #pragma unroll
  for (int t=0;t<4;t++)
    #pragma unroll
    for (int i=0;i<4;i++){ acc[t][i][0]=0.0f; acc[t][i][1]=0.0f; }

  for (int kt=0; kt<8; kt++){
    #pragma unroll
    for (int rep=0; rep<4; rep++){
      int idx = rep*128 + tid;
      int i = idx>>6, k = idx&63;
      const uint64_t* bp = inb + (((size_t)(n0+i))*8 + kt)*4;
      uint64_t w0=bp[0], w1=bp[1], w2=bp[2], w3=bp[3];
      float4 f;
      f.x = ((w0>>k)&1ull) ? 1.0f : 0.0f;
      f.y = ((w1>>k)&1ull) ? 1.0f : 0.0f;
      f.z = ((w2>>k)&1ull) ? 1.0f : 0.0f;
      f.w = ((w3>>k)&1ull) ? 1.0f : 0.0f;
      *(float4*)&sp[(i*64+k)*4] = f;
    }
    __syncthreads();
    const float* Wrow = W + (size_t)(kt*64)*128 + lane;
    #pragma unroll 4
    for (int q=0;q<64;q++){
      float wr0 = Wrow[(size_t)q*128];
      float wr1 = Wrow[(size_t)q*128 + 64];
      float4 s0 = *(const float4*)&sp[((g*4+0)*64+q)*4];
      float4 s1 = *(const float4*)&sp[((g*4+1)*64+q)*4];
      float4 s2 = *(const float4*)&sp[((g*4+2)*64+q)*4];
      float4 s3 = *(const float4*)&sp[((g*4+3)*64+q)*4];
      acc[0][0][0]=__fmaf_rn(s0.x,wr0,acc[0][0][0]); acc[0][0][1]=__fmaf_rn(s0.x,wr1,acc[0][0][1]);
      acc[1][0][0]=__fmaf_rn(s0.y,wr0,acc[1][0][0]); acc[1][0][1]=__fmaf_rn(s0.y,wr1,acc[1][0][1]);
      acc[2][0][0]=__fmaf_rn(s0.z,wr0,acc[2][0][0]); acc[2][0][1]=__fmaf_rn(s0.z,wr1,acc[2][0][1]);
      acc[3][0][0]=__fmaf_rn(s0.w,wr0,acc[3][0][0]); acc[3][0][1]=__fmaf_rn(s0.w,wr1,acc[3][0][1]);
      acc[0][1][0]=__fmaf_rn(s1.x,wr0,acc[0][1][0]); acc[0][1][1]=__fmaf_rn(s1.x,wr1,acc[0][1][1]);
      acc[1][1][0]=__fmaf_rn(s1.y,wr0,acc[1][1][0]); acc[1][1][1]=__fmaf_rn(s1.y,wr1,acc[1][1][1]);
      acc[2][1][0]=__fmaf_rn(s1.z,wr0,acc[2][1][0]); acc[2][1][1]=__fmaf_rn(s1.z,wr1,acc[2][1][1]);
      acc[3][1][0]=__fmaf_rn(s1.w,wr0,acc[3][1][0]); acc[3][1][1]=__fmaf_rn(s1.w,wr1,acc[3][1][1]);
      acc[0][2][0]=__fmaf_rn(s2.x,wr0,acc[0][2][0]); acc[0][2][1]=__fmaf_rn(s2.x,wr1,acc[0][2][1]);
      acc[1][2][0]=__fmaf_rn(s2.y,wr0,acc[1][2][0]); acc[1][2][1]=__fmaf_rn(s2.y,wr1,acc[1][2][1]);
      acc[2][2][0]=__fmaf_rn(s2.z,wr0,acc[2][2][0]); acc[2][2][1]=__fmaf_rn(s2.z,wr1,acc[2][2][1]);
      acc[3][2][0]=__fmaf_rn(s2.w,wr0,acc[3][2][0]); acc[3][2][1]=__fmaf_rn(s2.w,wr1,acc[3][2][1]);
      acc[0][3][0]=__fmaf_rn(s3.x,wr0,acc[0][3][0]); acc[0][3][1]=__fmaf_rn(s3.x,wr1,acc[0][3][1]);
      acc[1][3][0]=__fmaf_rn(s3.y,wr0,acc[1][3][0]); acc[1][3][1]=__fmaf_rn(s3.y,wr1,acc[1][3][1]);
      acc[2][3][0]=__fmaf_rn(s3.z,wr0,acc[2][3][0]); acc[2][3][1]=__fmaf_rn(s3.z,wr1,acc[2][3][1]);
      acc[3][3][0]=__fmaf_rn(s3.w,wr0,acc[3][3][0]); acc[3][3][1]=__fmaf_rn(s3.w,wr1,acc[3][3][1]);
    }
    __syncthreads();
  }

  #pragma unroll
  for (int i=0;i<4;i++){
    int node = n0 + g*4 + i;
    float v0 = 0.0f, v1 = 0.0f;
    uint64_t p0[4], p1[4];
    #pragma unroll
    for (int t=0;t<4;t++){
      bool s0 = lif32(v0, acc[t][i][0]);
      bool s1 = lif32(v1, acc[t][i][1]);
      p0[t] = __ballot(s0);
      p1[t] = __ballot(s1);
    }
    if (lane==0){
      uint64_t* d0 = outb + ((size_t)node*2 + 0)*4;
      uint64_t* d1 = outb + ((size_t)node*2 + 1)*4;
      #pragma unroll
      for (int t=0;t<4;t++){ d0[t]=p0[t]; d1[t]=p1[t]; }
    }
  }
}

// ---------------- Stage F: decoder + y + sigmoid ----------------
__global__ __launch_bounds__(128) void k_dec_y(const int* __restrict__ ns,
    const int* __restrict__ nt, const uint64_t* __restrict__ zs1b,
    const float* __restrict__ Wd, const float* __restrict__ bd,
    const float* __restrict__ wrec, float* __restrict__ out){
  int i = blockIdx.x;
  int tid = threadIdx.x;
  int row = tid>>6, j = tid&63;
  int node = row ? nt[i] : ns[i];
  float bdj = bd[j];
  double wrecj = (double)wrec[j];
  __shared__ uint64_t sw[2];

  uint32_t wlo[2][4], whi[2][4];
  const uint64_t* bp = zs1b + (size_t)node*8;
  #pragma unroll
  for (int g=0;g<2;g++)
    #pragma unroll
    for (int t=0;t<4;t++){
      uint64_t w8 = bp[g*4+t];
      wlo[g][t] = (uint32_t)w8;
      whi[g][t] = (uint32_t)(w8>>32);
      FORCE_V(wlo[g][t]); FORCE_V(whi[g][t]);
    }

  float acc[4] = {0.f,0.f,0.f,0.f};
  #pragma unroll
  for (int g=0;g<2;g++){
    #pragma unroll
    for (int h=0;h<2;h++){
      #pragma unroll
      for (int c=0;c<2;c++){
        float wr[16];
        #pragma unroll
        for (int q=0;q<16;q++) wr[q] = Wd[(size_t)(g*64+h*32+c*16+q)*64 + j];
        #pragma unroll
        for (int q=0;q<16;q++){
          int b = c*16+q;
          #pragma unroll
          for (int t=0;t<4;t++){
            uint32_t wv = h ? whi[g][t] : wlo[g][t];
            acc[t] = __fadd_rn(acc[t], bitmaskf(wv, b, wr[q]));
          }
        }
      }
    }
  }

  float v = 0.0f;
  double ysum = 0.0;
  #pragma unroll
  for (int t=0;t<4;t++){
    float a = __fadd_rn(acc[t], bdj);
    bool s = lif32(v, a);
    uint64_t bw = __ballot(s);
    if (j==0) sw[row] = bw;
    __syncthreads();
    uint64_t m = sw[0] & sw[1];
    __syncthreads();
    double term = ((m>>j)&1ull) ? wrecj : 0.0;
    #pragma unroll
    for (int off=1; off<64; off<<=1) term += shflxor_d(term, off);
    ysum += term;
  }
  if (tid==0) out[i] = (float)(1.0/(1.0 + exp(-0.25*ysum)));
}

// ---------------- Launcher ----------------
extern "C" void kernel_launch(void* const* d_in, const int* in_sizes, int n_in,
                              void* d_out, int out_size, void* d_ws, size_t ws_size,
                              hipStream_t stream) {
  const float* x    = (const float*)d_in[0];
  const float* W1   = (const float*)d_in[1];
  const float* W2   = (const float*)d_in[2];
  const float* Wd   = (const float*)d_in[3];
  const float* bd   = (const float*)d_in[4];
  const float* wrec = (const float*)d_in[5];
  const float* ew   = (const float*)d_in[6];
  const int* esrc   = (const int*)d_in[7];
  const int* edst   = (const int*)d_in[8];
  const int* ns     = (const int*)d_in[9];
  const int* nt     = (const int*)d_in[10];
  float* out = (float*)d_out;
  (void)in_sizes; (void)n_in; (void)out_size; (void)ws_size;

  // workspace layout (~41 MB)
  char* p = (char*)d_ws;
  uint64_t* inpb = (uint64_t*)p; p += (size_t)NN*16*8;
  uint64_t* hs0b = (uint64_t*)p; p += (size_t)NN*16*8;
  uint64_t* zs0b = (uint64_t*)p; p += (size_t)NN*16*8;
  uint64_t* hs1b = (uint64_t*)p; p += (size_t)NN*32*8;
  uint64_t* zs1b = (uint64_t*)p; p += (size_t)NN*8*8;
  int*   eidx = (int*)p;   p += (size_t)NE*4;
  int*   csrc = (int*)p;   p += (size_t)NE*4;
  float* cw   = (float*)p; p += (size_t)NE*4;
  int*   cnt  = (int*)p;   p += (size_t)(NN+2)*4;
  int*   rp   = (int*)p;   p += (size_t)(NN+2)*4;
  int*   cur  = (int*)p;   p += (size_t)(NN+2)*4;

  // host-side key chain: key=(0,42); kt=fold_in(key,t); k1,k2=split(kt)
  K8 K1, K2;
  for (int t=0;t<4;t++){
    uint32_t kt0,kt1;
    tf2x32(0u, 42u, 0u, (uint32_t)t, kt0, kt1);
#if JAX_PARTITIONABLE
    tf2x32(kt0, kt1, 0u, 0u, K1.a[t], K1.b[t]);
    tf2x32(kt0, kt1, 0u, 1u, K2.a[t], K2.b[t]);
#else
    uint32_t A0,B0,A1,B1;
    tf2x32(kt0, kt1, 0u, 2u, A0, B0);
    tf2x32(kt0, kt1, 1u, 3u, A1, B1);
    K1.a[t]=A0; K1.b[t]=A1; K2.a[t]=B0; K2.b[t]=B1;
#endif
  }

  // CSR build (deterministic via per-row sort by edge id)
  hipMemsetAsync(cnt, 0, (size_t)NN*4, stream);
  k_hist   <<<(NE+255)/256, 256, 0, stream>>>(edst, cnt);
  k_scan   <<<1, 1024, 0, stream>>>(cnt, rp, cur);
  k_scatter<<<(NE+255)/256, 256, 0, stream>>>(edst, cur, eidx);
  k_sortrow<<<(NN+255)/256, 256, 0, stream>>>(rp, eidx, esrc, ew, csrc, cw);

  // stage-major pipeline, all T=4 per kernel, LIF state in registers (fp32)
  k_pois_x<<<NN, 256, 0, stream>>>(x, inpb, K1);
  k_h0    <<<NN, 256, 0, stream>>>(rp, csrc, cw, inpb, hs0b, K2);
  k_z0    <<<NN/8, 256, 0, stream>>>(hs0b, W1, zs0b);
  k_h1    <<<NN, 512, 0, stream>>>(rp, csrc, cw, zs0b, hs0b, hs1b);
  k_z1    <<<NN/8, 128, 0, stream>>>(hs1b, W2, zs1b);
  k_dec_y <<<NL, 128, 0, stream>>>(ns, nt, zs1b, Wd, bd, wrec, out);
}

// Round 11
// 1588.105 us; speedup vs baseline: 1.9016x; 1.0285x over previous
//
#include <hip/hip_runtime.h>
#include <stdint.h>
#include <math.h>

// Problem constants
#define NN    50000       // N_NODES
#define NE    400000      // N_EDGES
#define NL    50000       // N_LINKS
#define TOT   12800000    // NN*256

#define JAX_PARTITIONABLE 1

struct K8 { uint32_t a[4]; uint32_t b[4]; };

// ---------------- Threefry-2x32 (20 rounds) ----------------
__host__ __device__ inline uint32_t rotl32(uint32_t x, int r){ return (x<<r)|(x>>(32-r)); }

__host__ __device__ inline void tf2x32(uint32_t k0, uint32_t k1, uint32_t x0, uint32_t x1,
                                       uint32_t &o0, uint32_t &o1) {
  uint32_t k2 = k0 ^ k1 ^ 0x1BD11BDAu;
  x0 += k0; x1 += k1;
#define TFR(r) { x0 += x1; x1 = rotl32(x1,(r)); x1 ^= x0; }
  TFR(13) TFR(15) TFR(26) TFR(6)
  x0 += k1; x1 += k2 + 1u;
  TFR(17) TFR(29) TFR(16) TFR(24)
  x0 += k2; x1 += k0 + 2u;
  TFR(13) TFR(15) TFR(26) TFR(6)
  x0 += k0; x1 += k1 + 3u;
  TFR(17) TFR(29) TFR(16) TFR(24)
  x0 += k1; x1 += k2 + 4u;
  TFR(13) TFR(15) TFR(26) TFR(6)
  x0 += k2; x1 += k0 + 5u;
#undef TFR
  o0 = x0; o1 = x1;
}

__device__ inline float u01(uint32_t b){
  return __uint_as_float((b>>9) | 0x3f800000u) - 1.0f;   // [1,2) - 1, exact
}

__device__ inline uint32_t jax_bits32(uint32_t ka, uint32_t kb, uint32_t i, uint32_t total){
#if JAX_PARTITIONABLE
  uint32_t o0,o1; tf2x32(ka,kb, 0u, i, o0,o1); return o0^o1;
#else
  uint32_t h = total>>1; uint32_t o0,o1;
  if (i < h){ tf2x32(ka,kb, i, i+h, o0,o1); return o0; }
  else      { tf2x32(ka,kb, i-h, i, o0,o1); return o1; }
#endif
}

__device__ inline double shflxor_d(double x, int m){
  union { double d; int i[2]; } u; u.d = x;
  u.i[0] = __shfl_xor(u.i[0], m, 64);
  u.i[1] = __shfl_xor(u.i[1], m, 64);
  return u.d;
}

// exact fp32 LIF step: v = fl(fl(v*0.5)+a); d = fl(v-0.2); s=(d>=0); v = s?d:v
__device__ inline bool lif32(float &v, float a){
  v = __fadd_rn(__fmul_rn(v, 0.5f), a);
  float d = __fsub_rn(v, 0.2f);
  bool s = (d >= 0.0f);
  v = s ? d : v;
  return s;
}

// force a value to live in a VGPR
#define FORCE_V(x) asm volatile("" : "+v"(x))

// wr if bit b of w set, else +0.0f — used in decoder (small)
__device__ inline float bitmaskf(uint32_t w, int b, float wr){
#if __has_builtin(__builtin_amdgcn_sbfe)
  int m = __builtin_amdgcn_sbfe((int)w, b, 1);
#else
  int m = ((int)(w << (31-b))) >> 31;
#endif
  return __int_as_float(__float_as_int(wr) & m);
}

// ---------------- CSR build (by dst), deterministic edge order ----------------
__global__ __launch_bounds__(256) void k_hist(const int* __restrict__ dst, int* __restrict__ cnt){
  int e = blockIdx.x*256 + threadIdx.x;
  if (e < NE) atomicAdd(&cnt[dst[e]], 1);
}

// wave-shuffle scan: 3 barriers per 1024-chunk (was ~20)
__global__ __launch_bounds__(1024) void k_scan(const int* __restrict__ cnt,
    int* __restrict__ rp, int* __restrict__ cur){
  __shared__ int ws[16];
  __shared__ int wp[17];
  int tid = threadIdx.x;
  int lane = tid & 63, wid = tid >> 6;
  int carry = 0;
  for (int base=0; base<NN; base+=1024){
    int v = (base+tid < NN) ? cnt[base+tid] : 0;
    int x = v;
    #pragma unroll
    for (int off=1; off<64; off<<=1){
      int u = __shfl_up(x, off, 64);
      if (lane >= off) x += u;
    }
    if (lane==63) ws[wid] = x;
    __syncthreads();
    if (wid==0){
      int s = (lane<16) ? ws[lane] : 0;
      #pragma unroll
      for (int off=1; off<16; off<<=1){
        int u = __shfl_up(s, off, 64);
        if (lane >= off) s += u;
      }
      if (lane<16) wp[lane+1] = s;
      if (lane==0) wp[0] = 0;
    }
    __syncthreads();
    int excl = x - v + wp[wid] + carry;
    if (base+tid < NN){ rp[base+tid] = excl; cur[base+tid] = excl; }
    carry += wp[16];
    __syncthreads();
  }
  if (tid==0) rp[NN] = NE;
}

__global__ __launch_bounds__(256) void k_scatter(const int* __restrict__ dst,
    int* __restrict__ cur, int* __restrict__ eidx){
  int e = blockIdx.x*256 + threadIdx.x;
  if (e < NE){ int p = atomicAdd(&cur[dst[e]], 1); eidx[p] = e; }
}

__global__ __launch_bounds__(256) void k_sortrow(const int* __restrict__ rp,
    int* __restrict__ eidx, const int* __restrict__ esrc, const float* __restrict__ ew,
    int* __restrict__ csrc, float* __restrict__ cw){
  int n = blockIdx.x*256 + threadIdx.x;
  if (n >= NN) return;
  int lo = rp[n], hi = rp[n+1];
  for (int a=lo+1; a<hi; a++){
    int k = eidx[a]; int b = a-1;
    while (b>=lo && eidx[b]>k){ eidx[b+1]=eidx[b]; b--; }
    eidx[b+1] = k;
  }
  for (int p=lo; p<hi; p++){ int e = eidx[p]; csrc[p] = esrc[e]; cw[p] = ew[e]; }
}

// Plane layouts (t innermost, 32B per (node,word)):
//   inpb/hs0b/zs0b : [node][w(4)][t(4)]   (NN*16 words)
//   hs1b           : [node][w(8)][t(4)]   (NN*32 words)
//   zs1b           : [node][w(2)][t(4)]   (NN*8  words)

// ---------------- Stage A: inp(t) = poisson(x, k1[t]) ----------------
__global__ __launch_bounds__(256) void k_pois_x(const float* __restrict__ x,
    uint64_t* __restrict__ bits, K8 K){
  int n = blockIdx.x, f = threadIdx.x;
  uint32_t i = (uint32_t)n*256u + (uint32_t)f;
  float xv = x[i];
  uint64_t pack[4];
  #pragma unroll
  for (int t=0;t<4;t++){
    bool b = (u01(jax_bits32(K.a[t],K.b[t], i, TOT)) <= xv);
    pack[t] = __ballot(b);
  }
  if ((f & 63)==0){
    uint64_t* dst = bits + ((size_t)n*4 + (f>>6))*4;
    #pragma unroll
    for (int t=0;t<4;t++) dst[t] = pack[t];
  }
}

// ---------------- Stage B: h0(t) fp32 gather (edge order) + poisson(h0,k2) ----------------
__global__ __launch_bounds__(256) void k_h0(const int* __restrict__ rp,
    const int* __restrict__ csrc, const float* __restrict__ cw,
    const uint64_t* __restrict__ inb, uint64_t* __restrict__ outb, K8 K){
  int n = blockIdx.x, f = threadIdx.x;
  int wi = f>>6, sh = f&63;
  int lo = rp[n], hi = rp[n+1];
  float a[4] = {0.f,0.f,0.f,0.f};
  for (int p=lo;p<hi;p++){
    int s = csrc[p]; float w = cw[p];
    const uint64_t* bp = inb + ((size_t)s*4 + wi)*4;   // 4 t-words, 32B contiguous
    uint64_t w0=bp[0], w1=bp[1], w2=bp[2], w3=bp[3];
    a[0] = __fadd_rn(a[0], ((w0>>sh)&1ull) ? w : 0.0f);
    a[1] = __fadd_rn(a[1], ((w1>>sh)&1ull) ? w : 0.0f);
    a[2] = __fadd_rn(a[2], ((w2>>sh)&1ull) ? w : 0.0f);
    a[3] = __fadd_rn(a[3], ((w3>>sh)&1ull) ? w : 0.0f);
  }
  uint32_t i = (uint32_t)n*256u + (uint32_t)f;
  uint64_t pack[4];
  #pragma unroll
  for (int t=0;t<4;t++){
    bool b = (u01(jax_bits32(K.a[t],K.b[t], i, TOT)) <= a[t]);
    pack[t] = __ballot(b);
  }
  if (sh==0){
    uint64_t* dst = outb + ((size_t)n*4 + wi)*4;
    #pragma unroll
    for (int t=0;t<4;t++) dst[t] = pack[t];
  }
}

// ---------------- Stage C: z0 = LIF_t(hs0 @ W1)  (K=256, M=256) ----------------
// 16 nodes/block (4 waves x 4-node group), 4 cols/thread (col = lane+64cc).
// Per q: 4 coalesced wr loads + 4 broadcast ds_read_b128 + 128 v_fma (1:16 ratio).
__global__ __launch_bounds__(256, 2) void k_z0(const uint64_t* __restrict__ inb,
    const float* __restrict__ W, uint64_t* __restrict__ outb){
  __shared__ __align__(16) float sp[16*64*4];    // [i(16)][k(64)][t(4)] 16KB
  int tid = threadIdx.x;
  int g = tid>>6, lane = tid&63;                 // wave = node group
  int n0 = blockIdx.x*16;
  float acc[4][4][4];                            // [t][i][cc]
  #pragma unroll
  for (int t=0;t<4;t++)
    #pragma unroll
    for (int i=0;i<4;i++)
      #pragma unroll
      for (int c=0;c<4;c++) acc[t][i][c]=0.0f;

  for (int kt=0; kt<4; kt++){
    #pragma unroll
    for (int rep=0; rep<4; rep++){
      int idx = rep*256 + tid;
      int i = idx>>6, k = idx&63;
      const uint64_t* bp = inb + (((size_t)(n0+i))*4 + kt)*4;
      uint64_t w0=bp[0], w1=bp[1], w2=bp[2], w3=bp[3];
      float4 f;
      f.x = ((w0>>k)&1ull) ? 1.0f : 0.0f;
      f.y = ((w1>>k)&1ull) ? 1.0f : 0.0f;
      f.z = ((w2>>k)&1ull) ? 1.0f : 0.0f;
      f.w = ((w3>>k)&1ull) ? 1.0f : 0.0f;
      *(float4*)&sp[(i*64+k)*4] = f;
    }
    __syncthreads();
    const float* Wrow = W + (size_t)(kt*64)*256 + lane;
    #pragma unroll 4
    for (int q=0;q<64;q++){
      const float* wb = Wrow + (size_t)q*256;
      float wr0 = wb[0], wr1 = wb[64], wr2 = wb[128], wr3 = wb[192];
      float4 s0 = *(const float4*)&sp[((g*4+0)*64+q)*4];
      float4 s1 = *(const float4*)&sp[((g*4+1)*64+q)*4];
      float4 s2 = *(const float4*)&sp[((g*4+2)*64+q)*4];
      float4 s3 = *(const float4*)&sp[((g*4+3)*64+q)*4];
      #define FMA4(ti, sv) \
        acc[ti][0][0]=__fmaf_rn(s0.sv,wr0,acc[ti][0][0]); acc[ti][0][1]=__fmaf_rn(s0.sv,wr1,acc[ti][0][1]); \
        acc[ti][0][2]=__fmaf_rn(s0.sv,wr2,acc[ti][0][2]); acc[ti][0][3]=__fmaf_rn(s0.sv,wr3,acc[ti][0][3]); \
        acc[ti][1][0]=__fmaf_rn(s1.sv,wr0,acc[ti][1][0]); acc[ti][1][1]=__fmaf_rn(s1.sv,wr1,acc[ti][1][1]); \
        acc[ti][1][2]=__fmaf_rn(s1.sv,wr2,acc[ti][1][2]); acc[ti][1][3]=__fmaf_rn(s1.sv,wr3,acc[ti][1][3]); \
        acc[ti][2][0]=__fmaf_rn(s2.sv,wr0,acc[ti][2][0]); acc[ti][2][1]=__fmaf_rn(s2.sv,wr1,acc[ti][2][1]); \
        acc[ti][2][2]=__fmaf_rn(s2.sv,wr2,acc[ti][2][2]); acc[ti][2][3]=__fmaf_rn(s2.sv,wr3,acc[ti][2][3]); \
        acc[ti][3][0]=__fmaf_rn(s3.sv,wr0,acc[ti][3][0]); acc[ti][3][1]=__fmaf_rn(s3.sv,wr1,acc[ti][3][1]); \
        acc[ti][3][2]=__fmaf_rn(s3.sv,wr2,acc[ti][3][2]); acc[ti][3][3]=__fmaf_rn(s3.sv,wr3,acc[ti][3][3]);
      FMA4(0, x) FMA4(1, y) FMA4(2, z) FMA4(3, w)
      #undef FMA4
    }
    __syncthreads();
  }

  #pragma unroll
  for (int i=0;i<4;i++){
    int node = n0 + g*4 + i;
    float v[4] = {0.f,0.f,0.f,0.f};
    #pragma unroll
    for (int t=0;t<4;t++){
      uint64_t b[4];
      #pragma unroll
      for (int c=0;c<4;c++){
        bool s = lif32(v[c], acc[t][i][c]);
        b[c] = __ballot(s);
      }
      if (lane==0){
        #pragma unroll
        for (int c=0;c<4;c++) outb[((size_t)node*4 + c)*4 + t] = b[c];
      }
    }
  }
}

// ---------------- Stage D: h1(t) gather over concat(zs0,hs0), LIF -> hs1 ----------------
__global__ __launch_bounds__(512) void k_h1(const int* __restrict__ rp,
    const int* __restrict__ csrc, const float* __restrict__ cw,
    const uint64_t* __restrict__ zs0b, const uint64_t* __restrict__ hs0b,
    uint64_t* __restrict__ hs1b){
  int n = blockIdx.x, f = threadIdx.x;           // f in [0,512)
  int wi = f>>6, sh = f&63;
  const uint64_t* plane = (wi<4) ? zs0b : hs0b;
  int wo = wi & 3;
  int lo = rp[n], hi = rp[n+1];
  float a[4] = {0.f,0.f,0.f,0.f};
  for (int p=lo;p<hi;p++){
    int s = csrc[p]; float w = cw[p];
    const uint64_t* bp = plane + ((size_t)s*4 + wo)*4;  // 32B contiguous
    uint64_t w0=bp[0], w1=bp[1], w2=bp[2], w3=bp[3];
    a[0] = __fadd_rn(a[0], ((w0>>sh)&1ull) ? w : 0.0f);
    a[1] = __fadd_rn(a[1], ((w1>>sh)&1ull) ? w : 0.0f);
    a[2] = __fadd_rn(a[2], ((w2>>sh)&1ull) ? w : 0.0f);
    a[3] = __fadd_rn(a[3], ((w3>>sh)&1ull) ? w : 0.0f);
  }
  float v = 0.0f;
  uint64_t pack[4];
  #pragma unroll
  for (int t=0;t<4;t++){
    bool s = lif32(v, a[t]);
    pack[t] = __ballot(s);
  }
  if (sh==0){
    uint64_t* dst = hs1b + ((size_t)n*8 + wi)*4;
    #pragma unroll
    for (int t=0;t<4;t++) dst[t] = pack[t];
  }
}

// ---------------- Stage E: z1 = LIF_t(hs1 @ W2)  (K=512, M=128) ----------------
// 16 nodes/block (2 waves, each wave = 2 node groups via half-waves),
// 4 cols/thread (col = (lane&31)+32cc). 2-address broadcast ds_read (free 2-way).
__global__ __launch_bounds__(128, 2) void k_z1(const uint64_t* __restrict__ inb,
    const float* __restrict__ W, uint64_t* __restrict__ outb){
  __shared__ __align__(16) float sp[16*64*4];    // [i(16)][k(64)][t(4)] 16KB
  int tid = threadIdx.x;
  int wv = tid>>6, lane = tid&63;
  int half = lane>>5, cl = lane&31;
  int gi = wv*2 + half;                          // node group of this lane
  int n0 = blockIdx.x*16;
  float acc[4][4][4];                            // [t][i][cc]
  #pragma unroll
  for (int t=0;t<4;t++)
    #pragma unroll
    for (int i=0;i<4;i++)
      #pragma unroll
      for (int c=0;c<4;c++) acc[t][i][c]=0.0f;

  for (int kt=0; kt<8; kt++){
    #pragma unroll
    for (int rep=0; rep<8; rep++){
      int idx = rep*128 + tid;
      int i = idx>>6, k = idx&63;
      const uint64_t* bp = inb + (((size_t)(n0+i))*8 + kt)*4;
      uint64_t w0=bp[0], w1=bp[1], w2=bp[2], w3=bp[3];
      float4 f;
      f.x = ((w0>>k)&1ull) ? 1.0f : 0.0f;
      f.y = ((w1>>k)&1ull) ? 1.0f : 0.0f;
      f.z = ((w2>>k)&1ull) ? 1.0f : 0.0f;
      f.w = ((w3>>k)&1ull) ? 1.0f : 0.0f;
      *(float4*)&sp[(i*64+k)*4] = f;
    }
    __syncthreads();
    const float* Wrow = W + (size_t)(kt*64)*128 + cl;
    #pragma unroll 4
    for (int q=0;q<64;q++){
      const float* wb = Wrow + (size_t)q*128;
      float wr0 = wb[0], wr1 = wb[32], wr2 = wb[64], wr3 = wb[96];
      float4 s0 = *(const float4*)&sp[((gi*4+0)*64+q)*4];
      float4 s1 = *(const float4*)&sp[((gi*4+1)*64+q)*4];
      float4 s2 = *(const float4*)&sp[((gi*4+2)*64+q)*4];
      float4 s3 = *(const float4*)&sp[((gi*4+3)*64+q)*4];
      #define FMA4(ti, sv) \
        acc[ti][0][0]=__fmaf_rn(s0.sv,wr0,acc[ti][0][0]); acc[ti][0][1]=__fmaf_rn(s0.sv,wr1,acc[ti][0][1]); \
        acc[ti][0][2]=__fmaf_rn(s0.sv,wr2,acc[ti][0][2]); acc[ti][0][3]=__fmaf_rn(s0.sv,wr3,acc[ti][0][3]); \
        acc[ti][1][0]=__fmaf_rn(s1.sv,wr0,acc[ti][1][0]); acc[ti][1][1]=__fmaf_rn(s1.sv,wr1,acc[ti][1][1]); \
        acc[ti][1][2]=__fmaf_rn(s1.sv,wr2,acc[ti][1][2]); acc[ti][1][3]=__fmaf_rn(s1.sv,wr3,acc[ti][1][3]); \
        acc[ti][2][0]=__fmaf_rn(s2.sv,wr0,acc[ti][2][0]); acc[ti][2][1]=__fmaf_rn(s2.sv,wr1,acc[ti][2][1]); \
        acc[ti][2][2]=__fmaf_rn(s2.sv,wr2,acc[ti][2][2]); acc[ti][2][3]=__fmaf_rn(s2.sv,wr3,acc[ti][2][3]); \
        acc[ti][3][0]=__fmaf_rn(s3.sv,wr0,acc[ti][3][0]); acc[ti][3][1]=__fmaf_rn(s3.sv,wr1,acc[ti][3][1]); \
        acc[ti][3][2]=__fmaf_rn(s3.sv,wr2,acc[ti][3][2]); acc[ti][3][3]=__fmaf_rn(s3.sv,wr3,acc[ti][3][3]);
      FMA4(0, x) FMA4(1, y) FMA4(2, z) FMA4(3, w)
      #undef FMA4
    }
    __syncthreads();
  }

  #pragma unroll
  for (int i=0;i<4;i++){
    int node = n0 + gi*4 + i;
    float v[4] = {0.f,0.f,0.f,0.f};
    #pragma unroll
    for (int t=0;t<4;t++){
      uint64_t b0,b1,b2,b3;
      { bool s = lif32(v[0], acc[t][i][0]); b0 = __ballot(s); }
      { bool s = lif32(v[1], acc[t][i][1]); b1 = __ballot(s); }
      { bool s = lif32(v[2], acc[t][i][2]); b2 = __ballot(s); }
      { bool s = lif32(v[3], acc[t][i][3]); b3 = __ballot(s); }
      if (cl==0){
        uint64_t m0, m1;
        if (half==0){
          m0 = (b0 & 0xffffffffull) | ((b1 & 0xffffffffull)<<32);
          m1 = (b2 & 0xffffffffull) | ((b3 & 0xffffffffull)<<32);
        } else {
          m0 = (b0>>32) | ((b1>>32)<<32);
          m1 = (b2>>32) | ((b3>>32)<<32);
        }
        outb[((size_t)node*2 + 0)*4 + t] = m0;
        outb[((size_t)node*2 + 1)*4 + t] = m1;
      }
    }
  }
}

// ---------------- Stage F: decoder + y + sigmoid ----------------
__global__ __launch_bounds__(128) void k_dec_y(const int* __restrict__ ns,
    const int* __restrict__ nt, const uint64_t* __restrict__ zs1b,
    const float* __restrict__ Wd, const float* __restrict__ bd,
    const float* __restrict__ wrec, float* __restrict__ out){
  int i = blockIdx.x;
  int tid = threadIdx.x;
  int row = tid>>6, j = tid&63;
  int node = row ? nt[i] : ns[i];
  float bdj = bd[j];
  double wrecj = (double)wrec[j];
  __shared__ uint64_t sw[2];

  uint32_t wlo[2][4], whi[2][4];
  const uint64_t* bp = zs1b + (size_t)node*8;
  #pragma unroll
  for (int g=0;g<2;g++)
    #pragma unroll
    for (int t=0;t<4;t++){
      uint64_t w8 = bp[g*4+t];
      wlo[g][t] = (uint32_t)w8;
      whi[g][t] = (uint32_t)(w8>>32);
      FORCE_V(wlo[g][t]); FORCE_V(whi[g][t]);
    }

  float acc[4] = {0.f,0.f,0.f,0.f};
  #pragma unroll
  for (int g=0;g<2;g++){
    #pragma unroll
    for (int h=0;h<2;h++){
      #pragma unroll
      for (int c=0;c<2;c++){
        float wr[16];
        #pragma unroll
        for (int q=0;q<16;q++) wr[q] = Wd[(size_t)(g*64+h*32+c*16+q)*64 + j];
        #pragma unroll
        for (int q=0;q<16;q++){
          int b = c*16+q;
          #pragma unroll
          for (int t=0;t<4;t++){
            uint32_t wv = h ? whi[g][t] : wlo[g][t];
            acc[t] = __fadd_rn(acc[t], bitmaskf(wv, b, wr[q]));
          }
        }
      }
    }
  }

  float v = 0.0f;
  double ysum = 0.0;
  #pragma unroll
  for (int t=0;t<4;t++){
    float a = __fadd_rn(acc[t], bdj);
    bool s = lif32(v, a);
    uint64_t bw = __ballot(s);
    if (j==0) sw[row] = bw;
    __syncthreads();
    uint64_t m = sw[0] & sw[1];
    __syncthreads();
    double term = ((m>>j)&1ull) ? wrecj : 0.0;
    #pragma unroll
    for (int off=1; off<64; off<<=1) term += shflxor_d(term, off);
    ysum += term;
  }
  if (tid==0) out[i] = (float)(1.0/(1.0 + exp(-0.25*ysum)));
}

// ---------------- Launcher ----------------
extern "C" void kernel_launch(void* const* d_in, const int* in_sizes, int n_in,
                              void* d_out, int out_size, void* d_ws, size_t ws_size,
                              hipStream_t stream) {
  const float* x    = (const float*)d_in[0];
  const float* W1   = (const float*)d_in[1];
  const float* W2   = (const float*)d_in[2];
  const float* Wd   = (const float*)d_in[3];
  const float* bd   = (const float*)d_in[4];
  const float* wrec = (const float*)d_in[5];
  const float* ew   = (const float*)d_in[6];
  const int* esrc   = (const int*)d_in[7];
  const int* edst   = (const int*)d_in[8];
  const int* ns     = (const int*)d_in[9];
  const int* nt     = (const int*)d_in[10];
  float* out = (float*)d_out;
  (void)in_sizes; (void)n_in; (void)out_size; (void)ws_size;

  // workspace layout (~41 MB)
  char* p = (char*)d_ws;
  uint64_t* inpb = (uint64_t*)p; p += (size_t)NN*16*8;
  uint64_t* hs0b = (uint64_t*)p; p += (size_t)NN*16*8;
  uint64_t* zs0b = (uint64_t*)p; p += (size_t)NN*16*8;
  uint64_t* hs1b = (uint64_t*)p; p += (size_t)NN*32*8;
  uint64_t* zs1b = (uint64_t*)p; p += (size_t)NN*8*8;
  int*   eidx = (int*)p;   p += (size_t)NE*4;
  int*   csrc = (int*)p;   p += (size_t)NE*4;
  float* cw   = (float*)p; p += (size_t)NE*4;
  int*   cnt  = (int*)p;   p += (size_t)(NN+2)*4;
  int*   rp   = (int*)p;   p += (size_t)(NN+2)*4;
  int*   cur  = (int*)p;   p += (size_t)(NN+2)*4;

  // host-side key chain: key=(0,42); kt=fold_in(key,t); k1,k2=split(kt)
  K8 K1, K2;
  for (int t=0;t<4;t++){
    uint32_t kt0,kt1;
    tf2x32(0u, 42u, 0u, (uint32_t)t, kt0, kt1);
#if JAX_PARTITIONABLE
    tf2x32(kt0, kt1, 0u, 0u, K1.a[t], K1.b[t]);
    tf2x32(kt0, kt1, 0u, 1u, K2.a[t], K2.b[t]);
#else
    uint32_t A0,B0,A1,B1;
    tf2x32(kt0, kt1, 0u, 2u, A0, B0);
    tf2x32(kt0, kt1, 1u, 3u, A1, B1);
    K1.a[t]=A0; K1.b[t]=A1; K2.a[t]=B0; K2.b[t]=B1;
#endif
  }

  // CSR build (deterministic via per-row sort by edge id)
  hipMemsetAsync(cnt, 0, (size_t)NN*4, stream);
  k_hist   <<<(NE+255)/256, 256, 0, stream>>>(edst, cnt);
  k_scan   <<<1, 1024, 0, stream>>>(cnt, rp, cur);
  k_scatter<<<(NE+255)/256, 256, 0, stream>>>(edst, cur, eidx);
  k_sortrow<<<(NN+255)/256, 256, 0, stream>>>(rp, eidx, esrc, ew, csrc, cw);

  // stage-major pipeline, all T=4 per kernel, LIF state in registers (fp32)
  k_pois_x<<<NN, 256, 0, stream>>>(x, inpb, K1);
  k_h0    <<<NN, 256, 0, stream>>>(rp, csrc, cw, inpb, hs0b, K2);
  k_z0    <<<NN/16, 256, 0, stream>>>(hs0b, W1, zs0b);
  k_h1    <<<NN, 512, 0, stream>>>(rp, csrc, cw, zs0b, hs0b, hs1b);
  k_z1    <<<NN/16, 128, 0, stream>>>(hs1b, W2, zs1b);
  k_dec_y <<<NL, 128, 0, stream>>>(ns, nt, zs1b, Wd, bd, wrec, out);
}